// Round 17
// baseline (387.466 us; speedup 1.0000x reference)
//
#include <hip/hip_runtime.h>
#include <hip/hip_bf16.h>
#include <cstdint>

// Model constants
#define B_SZ 128
#define L_SZ 150
#define E_SZ 150
#define HIDN 128
#define M_TOK (B_SZ*L_SZ)   // 19200
#define G3 384              // 3*HID gates
#define NFC 2304            // capsule-FC input count
#define NCH 72              // n-chunks per b (32 n each)

typedef __attribute__((ext_vector_type(8))) short bf16x8;
typedef __attribute__((ext_vector_type(4))) float f32x4;

__device__ __forceinline__ float sigm(float x){ return 1.f/(1.f+__expf(-x)); }

__device__ __forceinline__ void storeval(float* p, float v){ *p = v; }
__device__ __forceinline__ void storeval(__hip_bfloat16* p, float v){ *p = __float2bfloat16(v); }

// ---------------- kernel 1: c[t][32] = softmax over last-4 of code[x[t]] ----------------
__global__ void softmax_c_kernel(const float* __restrict__ code, const int* __restrict__ x,
                                 float* __restrict__ c){
  int idx = blockIdx.x*blockDim.x + threadIdx.x;
  if (idx >= M_TOK*8) return;
  int t = idx >> 3, j = idx & 7;
  int tok = x[t];
  const float* p = code + ((size_t)tok*32 + j*4);
  float a0=p[0],a1=p[1],a2=p[2],a3=p[3];
  float mx = fmaxf(fmaxf(a0,a1),fmaxf(a2,a3));
  float e0=__expf(a0-mx),e1=__expf(a1-mx),e2=__expf(a2-mx),e3=__expf(a3-mx);
  float inv = 1.f/(e0+e1+e2+e3);
  float* q = c + ((size_t)t*32 + j*4);
  q[0]=e0*inv; q[1]=e1*inv; q[2]=e2*inv; q[3]=e3*inv;
}

// ---------------- kernel 2: emb bf16 padded ----------------
__global__ void embed_bf16_kernel(const float* __restrict__ c, const float* __restrict__ cb,
                                  __hip_bfloat16* __restrict__ A0, int Kp){
  int idx = blockIdx.x*blockDim.x + threadIdx.x;
  if (idx >= M_TOK*160) return;
  int t = idx / 160; int e = idx - t*160;
  float acc = 0.f;
  if (e < E_SZ){
    const float* cr = c + (size_t)t*32;
    #pragma unroll
    for (int i=0;i<32;i++) acc += cr[i]*cb[i*E_SZ + e];
  }
  A0[(size_t)t*Kp + e] = __float2bfloat16(acc);
}

// ---------------- weight fp32->bf16 (K-padded) ----------------
__global__ void convW_kernel(const float* __restrict__ src, __hip_bfloat16* __restrict__ dst,
                             int N, int K, int Kp){
  int idx = blockIdx.x*blockDim.x + threadIdx.x;
  if (idx >= N*Kp) return;
  int n = idx / Kp; int k = idx - n*Kp;
  float v = (k < K) ? src[(size_t)n*K + k] : 0.f;
  dst[idx] = __float2bfloat16(v);
}

// ---------------- capsule-conv weight prep ----------------
__global__ void convWc_kernel(const float* __restrict__ w, __hip_bfloat16* __restrict__ dst,
                              int NCAPS){
  int KP = 12*NCAPS;
  int idx = blockIdx.x*blockDim.x + threadIdx.x;
  if (idx >= 128*KP) return;
  int j = idx / KP; int rem = idx - j*KP;
  int k = rem/(4*NCAPS); int r2 = rem - k*4*NCAPS; int n = r2>>2; int xx = r2&3;
  int m = j>>2, d = j&3;
  dst[idx] = __float2bfloat16(w[(size_t)(((k*NCAPS+n)*4+xx)*4+d)*32 + m]);
}

// ---------------- kernel 3: MFMA GEMM (input projections) ----------------
__global__ __launch_bounds__(256) void gemm_mfma_kernel(
    const __hip_bfloat16* __restrict__ A, const __hip_bfloat16* __restrict__ W,
    const float* __restrict__ bias, float* __restrict__ out, int Kp)
{
  __shared__ __hip_bfloat16 As[128*32];
  __shared__ __hip_bfloat16 Bs[128*32];
  int tid = threadIdx.x;
  int m0 = blockIdx.y*128, n0 = blockIdx.x*128;
  int lane = tid & 63, wid = tid >> 6;
  int wr = wid >> 1, wc = wid & 1;
  int srow = tid >> 2, scol = (tid & 3) * 8;

  f32x4 acc[4][4];
  #pragma unroll
  for (int i=0;i<4;i++)
    #pragma unroll
    for (int j=0;j<4;j++) acc[i][j] = (f32x4){0.f,0.f,0.f,0.f};

  int r = lane & 15, kq = (lane >> 4) * 8;

  for (int k0 = 0; k0 < Kp; k0 += 32){
    __builtin_amdgcn_global_load_lds(
      (const __attribute__((address_space(1))) void*)(A + (size_t)(m0+srow)*Kp + k0 + scol),
      (__attribute__((address_space(3))) void*)(As + tid*8), 16, 0, 0);
    __builtin_amdgcn_global_load_lds(
      (const __attribute__((address_space(1))) void*)(A + (size_t)(m0+64+srow)*Kp + k0 + scol),
      (__attribute__((address_space(3))) void*)(As + 2048 + tid*8), 16, 0, 0);
    __builtin_amdgcn_global_load_lds(
      (const __attribute__((address_space(1))) void*)(W + (size_t)(n0+srow)*Kp + k0 + scol),
      (__attribute__((address_space(3))) void*)(Bs + tid*8), 16, 0, 0);
    __builtin_amdgcn_global_load_lds(
      (const __attribute__((address_space(1))) void*)(W + (size_t)(n0+64+srow)*Kp + k0 + scol),
      (__attribute__((address_space(3))) void*)(Bs + 2048 + tid*8), 16, 0, 0);
    __syncthreads();

    bf16x8 aF[4], bF[4];
    #pragma unroll
    for (int mi=0;mi<4;mi++) aF[mi] = *(const bf16x8*)(As + (wr*64 + mi*16 + r)*32 + kq);
    #pragma unroll
    for (int nj=0;nj<4;nj++) bF[nj] = *(const bf16x8*)(Bs + (wc*64 + nj*16 + r)*32 + kq);
    #pragma unroll
    for (int mi=0;mi<4;mi++)
      #pragma unroll
      for (int nj=0;nj<4;nj++)
        acc[mi][nj] = __builtin_amdgcn_mfma_f32_16x16x32_bf16(aF[mi], bF[nj], acc[mi][nj], 0, 0, 0);
    __syncthreads();
  }

  #pragma unroll
  for (int nj=0;nj<4;nj++){
    int n = n0 + wc*64 + nj*16 + (lane & 15);
    int dir = (n >= G3) ? 1 : 0; int g = n - dir*G3;
    float bv = bias[n];
    #pragma unroll
    for (int mi=0;mi<4;mi++){
      #pragma unroll
      for (int r2=0;r2<4;r2++){
        int m = m0 + wr*64 + mi*16 + (lane>>4)*4 + r2;
        out[((size_t)dir*M_TOK + m)*G3 + g] = acc[mi][nj][r2] + bv;
      }
    }
  }
}

// ---------------- kernel 4: GRU scan v8 — MFMA + counted-wait barrier ----------------
// R17: the end-of-step __syncthreads() drains vmcnt(0) (compiler semantics), which
// serializes the 6 in-flight gi prefetch loads every step (R11 null explained).
// Replace with inline-asm `s_waitcnt lgkmcnt(0); s_barrier`: LDS h-exchange is
// drained (cross-wave visibility), global gi loads stay in flight across the
// barrier and are waited only at their (same-wave) consumption next iteration.
template <typename OT>
__global__ __launch_bounds__(512, 2) void gru_scan_mfma_kernel(
    const float* __restrict__ gi,            // [2][19200][384]
    const __hip_bfloat16* __restrict__ whhb, // [2][384][128] bf16
    const float* __restrict__ bhh,           // [2][384]
    OT* __restrict__ out, int rowStride, size_t dirOffset)
{
  int bx = blockIdx.x; int dir = bx>>7; int b = bx&127;
  int tid = threadIdx.x; int wid = tid>>6, lane = tid&63;
  int colr = lane & 15;
  int rowq = lane >> 4;
  __shared__ __hip_bfloat16 h_lds[2][2048];

  for (int i = tid; i < 4096; i += 512)
    ((__hip_bfloat16*)h_lds)[i] = __float2bfloat16(0.f);

  bf16x8 wF[3][4];
  #pragma unroll
  for (int g=0;g<3;g++)
    #pragma unroll
    for (int kc=0;kc<4;kc++){
      int orow = g*128 + wid*16 + colr;
      wF[g][kc] = *(const bf16x8*)(whhb + ((size_t)dir*G3 + orow)*HIDN + kc*32 + rowq*8);
    }
  #pragma unroll
  for (int g=0;g<3;g++)
    #pragma unroll
    for (int kc=0;kc<4;kc++)
      asm volatile("" : "+v"(wF[g][kc]));

  float bg_[3];
  #pragma unroll
  for (int g=0;g<3;g++)
    bg_[g] = bhh[dir*G3 + g*128 + wid*16 + colr];

  float h_old = 0.f;
  bool valid = (lane < 16);
  int j = wid*16 + colr;
  int boff = ((j>>5)*64 + ((j>>3)&3)*16)*16 + (j&7)*2;

  const float* gib = gi + ((size_t)dir*M_TOK + (size_t)b*L_SZ)*G3;

  float gv[3];
  {
    int t0 = dir ? (L_SZ-1) : 0;
    #pragma unroll
    for (int g=0;g<3;g++)
      gv[g] = valid ? gib[(size_t)t0*G3 + g*128 + j] : 0.f;
  }
  __syncthreads();

  int cur = 0;
  for (int s=0; s<L_SZ; ++s){
    int t = dir ? (L_SZ-1-s) : s;
    float gn[3] = {};
    if (s+1 < L_SZ){
      int tn = dir ? (t-1) : (t+1);
      #pragma unroll
      for (int g=0;g<3;g++)
        if (valid) gn[g] = gib[(size_t)tn*G3 + g*128 + j];
    }

    bf16x8 aF[4];
    #pragma unroll
    for (int kc=0;kc<4;kc++)
      aF[kc] = *(const bf16x8*)((const char*)h_lds[cur] + (kc*64 + lane)*16);
    f32x4 acc[3];
    #pragma unroll
    for (int g=0;g<3;g++) acc[g] = (f32x4){0.f,0.f,0.f,0.f};
    #pragma unroll
    for (int kc=0;kc<4;kc++)
      #pragma unroll
      for (int g=0;g<3;g++)
        acc[g] = __builtin_amdgcn_mfma_f32_16x16x32_bf16(aF[kc], wF[g][kc], acc[g], 0, 0, 0);

    if (valid){
      float rr = sigm(gv[0] + acc[0][0] + bg_[0]);
      float zz = sigm(gv[1] + acc[1][0] + bg_[1]);
      float xn = gv[2] + rr*(acc[2][0] + bg_[2]);
      float e2 = __expf(2.f*xn);
      float nn = 1.f - 2.f/(e2+1.f);
      float hnew = (1.f-zz)*nn + zz*h_old;
      h_old = hnew;
      *(__hip_bfloat16*)((char*)h_lds[cur^1] + boff) = __float2bfloat16(hnew);
      storeval(&out[(size_t)(b*L_SZ + t)*rowStride + (size_t)dir*dirOffset + j], hnew);
    }
    // counted-wait barrier: drain LDS only; leave gi prefetch loads in flight.
    asm volatile("s_waitcnt lgkmcnt(0)\n\ts_barrier" ::: "memory");
    #pragma unroll
    for (int g=0;g<3;g++) gv[g] = gn[g];
    cur ^= 1;
  }
}

// ---------------- kernel 5: ln0 -> in_t0[b][t][a][n][x] bf16 ----------------
__global__ void ln0_kernel(const float* __restrict__ h2, const float* __restrict__ g,
                           const float* __restrict__ bt, __hip_bfloat16* __restrict__ in_t0){
  int idx = blockIdx.x*blockDim.x + threadIdx.x;
  if (idx >= B_SZ*8*L_SZ) return;
  int t = idx % L_SZ; int bn = idx / L_SZ; int n = bn & 7; int b = bn >> 3;
  const float* f0 = h2 + (size_t)(b*L_SZ+t)*HIDN + n*16;
  const float* f1 = f0 + (size_t)M_TOK*HIDN;
  float v[16]; float s = 0.f;
  #pragma unroll
  for (int d=0;d<16;d++){ v[d] = f0[d] + f1[d]; s += v[d]; }
  float mu = s*(1.f/16.f);
  float q = 0.f;
  #pragma unroll
  for (int d=0;d<16;d++){ float df = v[d]-mu; q += df*df; }
  float rs = rsqrtf(q*(1.f/16.f) + 1e-5f);
  __hip_bfloat16* o = in_t0 + (size_t)b*19200 + t*128 + n*4;
  #pragma unroll
  for (int dd=0;dd<16;dd++){
    int a = dd>>2, xx = dd&3;
    o[a*32 + xx] = __float2bfloat16((v[dd]-mu)*rs*g[dd] + bt[dd]);
  }
}

// ---------------- kernel 6: capsule conv as MFMA GEMM with fused LN epilogue ----------------
template<int CONV>
__global__ __launch_bounds__(256) void caps_mfma_kernel(
    const __hip_bfloat16* __restrict__ A, const __hip_bfloat16* __restrict__ W,
    const float* __restrict__ gam, const float* __restrict__ bet,
    void* __restrict__ outv)
{
  constexpr int KP   = (CONV==1) ? 96 : 384;
  constexpr int KTAP = (CONV==1) ? 32 : 128;
  constexpr int S    = (CONV==1) ? 2 : 1;
  constexpr int H    = (CONV==1) ? 74 : 72;
  constexpr int RSTR = (CONV==1) ? 128 : 512;
  constexpr int BSTR = (CONV==1) ? 19200 : 37888;
  __shared__ __hip_bfloat16 As[128*32];
  __shared__ __hip_bfloat16 Bs[128*32];
  int tid = threadIdx.x;
  int m0 = blockIdx.x*128;
  int lane = tid&63, wid = tid>>6;
  int wr = wid>>1, wc = wid&1;
  int srow = tid>>2, scol = (tid&3)*8;

  int row1 = m0 + srow, row2 = row1 + 64;
  int bh1 = row1>>2, a1 = row1&3; int b1 = bh1/H, h1 = bh1 - b1*H;
  int bh2 = row2>>2, a2 = row2&3; int b2 = bh2/H, h2_ = bh2 - b2*H;
  const __hip_bfloat16* arow1 = A + (size_t)b1*BSTR + (size_t)(h1*S)*RSTR + a1*KTAP;
  const __hip_bfloat16* arow2 = A + (size_t)b2*BSTR + (size_t)(h2_*S)*RSTR + a2*KTAP;

  f32x4 acc[4][4];
  #pragma unroll
  for (int i=0;i<4;i++)
    #pragma unroll
    for (int j=0;j<4;j++) acc[i][j] = (f32x4){0.f,0.f,0.f,0.f};

  int r = lane&15, kq = (lane>>4)*8;

  for (int k0=0; k0<KP; k0+=32){
    int tap = k0/KTAP;
    int off = k0 - tap*KTAP + scol;
    __builtin_amdgcn_global_load_lds(
      (const __attribute__((address_space(1))) void*)(arow1 + tap*RSTR + off),
      (__attribute__((address_space(3))) void*)(As + tid*8), 16, 0, 0);
    __builtin_amdgcn_global_load_lds(
      (const __attribute__((address_space(1))) void*)(arow2 + tap*RSTR + off),
      (__attribute__((address_space(3))) void*)(As + 2048 + tid*8), 16, 0, 0);
    __builtin_amdgcn_global_load_lds(
      (const __attribute__((address_space(1))) void*)(W + (size_t)srow*KP + k0 + scol),
      (__attribute__((address_space(3))) void*)(Bs + tid*8), 16, 0, 0);
    __builtin_amdgcn_global_load_lds(
      (const __attribute__((address_space(1))) void*)(W + (size_t)(64+srow)*KP + k0 + scol),
      (__attribute__((address_space(3))) void*)(Bs + 2048 + tid*8), 16, 0, 0);
    __syncthreads();

    bf16x8 aF[4], bF[4];
    #pragma unroll
    for (int mi=0;mi<4;mi++) aF[mi] = *(const bf16x8*)(As + (wr*64 + mi*16 + r)*32 + kq);
    #pragma unroll
    for (int nj=0;nj<4;nj++) bF[nj] = *(const bf16x8*)(Bs + (wc*64 + nj*16 + r)*32 + kq);
    #pragma unroll
    for (int mi=0;mi<4;mi++)
      #pragma unroll
      for (int nj=0;nj<4;nj++)
        acc[mi][nj] = __builtin_amdgcn_mfma_f32_16x16x32_bf16(aF[mi], bF[nj], acc[mi][nj], 0, 0, 0);
    __syncthreads();
  }

  #pragma unroll
  for (int mi=0;mi<4;mi++)
    #pragma unroll
    for (int nj=0;nj<4;nj++){
      int jj = wc*64 + nj*16 + (lane&15);
      int rowb = m0 + wr*64 + mi*16 + (lane>>4)*4;
      float vv[4];
      #pragma unroll
      for (int r2=0;r2<4;r2++) vv[r2] = acc[mi][nj][r2]*(1.f/32.f);
      float s = vv[0]+vv[1]+vv[2]+vv[3];
      s += __shfl_xor(s,1); s += __shfl_xor(s,2);
      float mu = s*(1.f/16.f);
      float q = 0.f;
      #pragma unroll
      for (int r2=0;r2<4;r2++){ float df = vv[r2]-mu; q += df*df; }
      q += __shfl_xor(q,1); q += __shfl_xor(q,2);
      float rs = rsqrtf(q*(1.f/16.f) + 1e-5f);
      int d = jj&3;
      #pragma unroll
      for (int r2=0;r2<4;r2++){
        float o = (vv[r2]-mu)*rs*gam[r2*4+d] + bet[r2*4+d];
        if constexpr (CONV==1){
          ((__hip_bfloat16*)outv)[(size_t)(rowb+r2)*128 + jj] = __float2bfloat16(o);
        } else {
          int rw = rowb + r2; int bh = rw>>2, a = rw&3; int bb = bh/H, hh = bh - bb*H;
          ((float*)outv)[((size_t)bb*NFC + (jj>>2)*H + hh)*16 + a*4 + d] = o;
        }
      }
    }
}

// ---------------- kernel 7: transpose wfc -> wT[n][m][d][x] ----------------
__global__ void transposeW_kernel(const float* __restrict__ wfc, float* __restrict__ wT){
  int idx = blockIdx.x*blockDim.x + threadIdx.x;
  if (idx >= NFC*240) return;
  int n = idx / 240; int r = idx - n*240;
  int m = r >> 4; int dd = (r >> 2) & 3; int xx = r & 3;
  wT[idx] = wfc[(size_t)((n*4+xx)*4+dd)*15 + m];
}

// ---------------- kernel 8: routing pass v2 (R14 best) — (m,nl)-per-thread ----------------
#define RP_WTS 0        // 32 rows x 244 floats (7808) / accs 240x33 (7920) union
#define RP_FIS 7920     // 32 x 20
#define RP_V3S 8560     // 240
#define RP_LG  8800     // 32 x 17
#define RP_TOT 9344
template<int WITH_SM>
__global__ __launch_bounds__(512) void route_pass_kernel(
    const float* __restrict__ v2, const float* __restrict__ wT,
    const float* __restrict__ v3, float* __restrict__ part)
{
  int ch = blockIdx.x, b = blockIdx.y;
  int tid = threadIdx.x;
  int m = tid >> 5;          // 0..15 (15 inactive)
  int nl = tid & 31;
  int n0 = ch*32;
  bool act = (m < 15);

  __shared__ float smem[RP_TOT];
  float* wTs  = smem + RP_WTS;   // row stride 244 floats (61 f4)
  float* accs = smem + RP_WTS;   // stride 33, union with wTs
  float* fis  = smem + RP_FIS;   // row stride 20 floats (5 f4)
  float* v3s  = smem + RP_V3S;
  float* lgs  = smem + RP_LG;    // [32][17]

  for (int i=tid; i<32*60; i+=512){
    int row = i/60, q = i - row*60;
    ((float4*)wTs)[row*61 + q] = ((const float4*)(wT + (size_t)n0*240))[row*60 + q];
  }
  for (int i=tid; i<128; i+=512){
    int row = i>>2, q = i&3;
    ((float4*)fis)[row*5 + q] = ((const float4*)(v2 + ((size_t)b*NFC + n0)*16))[i];
  }
  if (WITH_SM && tid < 240) v3s[tid] = v3[(size_t)b*240 + tid];
  __syncthreads();

  float vt[16];
  float qk = 1.f/15.f;
  if (act){
    float4 fiv[4], wv[4];
    #pragma unroll
    for (int a=0;a<4;a++) fiv[a] = *(const float4*)&fis[nl*20 + a*4];
    #pragma unroll
    for (int d=0;d<4;d++) wv[d] = *(const float4*)&wTs[nl*244 + m*16 + d*4];
    #pragma unroll
    for (int a=0;a<4;a++)
      #pragma unroll
      for (int d=0;d<4;d++)
        vt[a*4+d] = fiv[a].x*wv[d].x + fiv[a].y*wv[d].y + fiv[a].z*wv[d].z + fiv[a].w*wv[d].w;
    if (WITH_SM){
      float lg = 0.f;
      #pragma unroll
      for (int ad=0;ad<16;ad++) lg += vt[ad]*v3s[m*16+ad];
      lgs[nl*17 + m] = lg*0.25f;
    }
  }
  if (WITH_SM){
    __syncthreads();
    if (act){
      float l[15];
      #pragma unroll
      for (int mm=0;mm<15;mm++) l[mm] = lgs[nl*17 + mm];
      float mx = l[0];
      #pragma unroll
      for (int mm=1;mm<15;mm++) mx = fmaxf(mx, l[mm]);
      float se = 0.f;
      #pragma unroll
      for (int mm=0;mm<15;mm++){ l[mm] = __expf(l[mm]-mx); se += l[mm]; }
      float inv = 1.f/se;
      float s2 = 0.f;
      #pragma unroll
      for (int mm=0;mm<15;mm++) s2 += l[mm]*inv;
      qk = (l[m]*inv)/(s2 + 1e-10f);
    }
  }
  __syncthreads();   // wTs reads complete -> safe to overwrite with accs
  if (act){
    #pragma unroll
    for (int ad=0;ad<16;ad++)
      accs[(m*16+ad)*33 + nl] = qk*vt[ad];
  }
  __syncthreads();
  if (tid < 240){
    float s = 0.f;
    #pragma unroll
    for (int k=0;k<32;k++) s += accs[tid*33 + k];
    part[((size_t)b*NCH + ch)*240 + tid] = s;
  }
}

// ---------------- kernel 9: reduce partials -> LN -> v3 ----------------
__global__ __launch_bounds__(240) void reduce_v3_kernel(
    const float* __restrict__ part, const float* __restrict__ g,
    const float* __restrict__ bt, float* __restrict__ v3)
{
  int b = blockIdx.x; int tid = threadIdx.x;
  int ad = tid & 15;
  float s = 0.f;
  for (int ch=0; ch<NCH; ++ch) s += part[((size_t)b*NCH + ch)*240 + tid];
  float tot = s;
  tot += __shfl_xor(tot,1); tot += __shfl_xor(tot,2);
  tot += __shfl_xor(tot,4); tot += __shfl_xor(tot,8);
  float mu = tot*(1.f/16.f);
  float df = s - mu;
  float q = df*df;
  q += __shfl_xor(q,1); q += __shfl_xor(q,2);
  q += __shfl_xor(q,4); q += __shfl_xor(q,8);
  float rs = rsqrtf(q*(1.f/16.f) + 1e-5f);
  v3[(size_t)b*240 + tid] = df*rs*g[ad] + bt[ad];
}

// ---------------- kernel 10: reduce partials -> LN -> norm head -> out ----------------
__global__ __launch_bounds__(240) void reduce_out_kernel(
    const float* __restrict__ part, const float* __restrict__ g,
    const float* __restrict__ bt, float* __restrict__ out)
{
  int b = blockIdx.x; int tid = threadIdx.x;
  int m = tid >> 4; int ad = tid & 15;
  float s = 0.f;
  for (int ch=0; ch<NCH; ++ch) s += part[((size_t)b*NCH + ch)*240 + tid];
  float tot = s;
  tot += __shfl_xor(tot,1); tot += __shfl_xor(tot,2);
  tot += __shfl_xor(tot,4); tot += __shfl_xor(tot,8);
  float mu = tot*(1.f/16.f);
  float df = s - mu;
  float q = df*df;
  q += __shfl_xor(q,1); q += __shfl_xor(q,2);
  q += __shfl_xor(q,4); q += __shfl_xor(q,8);
  float rs = rsqrtf(q*(1.f/16.f) + 1e-5f);
  float v = df*rs*g[ad] + bt[ad];
  float q2 = v*v;
  q2 += __shfl_xor(q2,1); q2 += __shfl_xor(q2,2);
  q2 += __shfl_xor(q2,4); q2 += __shfl_xor(q2,8);
  if (ad == 0) out[(size_t)b*15 + m] = q2/(1.f+q2);
}

// =================================================================================
extern "C" void kernel_launch(void* const* d_in, const int* in_sizes, int n_in,
                              void* d_out, int out_size, void* d_ws, size_t ws_size,
                              hipStream_t stream) {
  const float* code     = (const float*)d_in[0];
  const float* codebook = (const float*)d_in[1];
  const float* w_ih0    = (const float*)d_in[2];
  const float* w_hh0    = (const float*)d_in[3];
  const float* b_ih0    = (const float*)d_in[4];
  const float* b_hh0    = (const float*)d_in[5];
  const float* w_ih1    = (const float*)d_in[6];
  const float* w_hh1    = (const float*)d_in[7];
  const float* b_ih1    = (const float*)d_in[8];
  const float* b_hh1    = (const float*)d_in[9];
  const float* ln0g     = (const float*)d_in[10];
  const float* ln0b     = (const float*)d_in[11];
  const float* w1       = (const float*)d_in[12];
  const float* ln1g     = (const float*)d_in[13];
  const float* ln1b     = (const float*)d_in[14];
  const float* w2       = (const float*)d_in[15];
  const float* ln2g     = (const float*)d_in[16];
  const float* ln2b     = (const float*)d_in[17];
  const float* wfc      = (const float*)d_in[18];
  const float* lnfg     = (const float*)d_in[19];
  const float* lnfb     = (const float*)d_in[20];
  const int*   x        = (const int*)d_in[21];
  float* out = (float*)d_out;
  float* ws  = (float*)d_ws;

  float* gi   = ws + 0;
  __hip_bfloat16* v1t = (__hip_bfloat16*)(ws + 0);
  float* v2f  = ws + 4849664;
  float* wT   = ws + 9568256;
  float* part = ws + 10121216;
  __hip_bfloat16* h1b = (__hip_bfloat16*)(ws + 14745600);
  float* h2   = ws + 17203200;
  float* c_buf= ws + 17203200;
  __hip_bfloat16* in_t0 = (__hip_bfloat16*)(ws + 22118400);
  __hip_bfloat16* A0b = (__hip_bfloat16*)(ws + 22118400);
  __hip_bfloat16* Whh0b = (__hip_bfloat16*)(ws + 23654400);
  __hip_bfloat16* Whh1b = (__hip_bfloat16*)(ws + 23703552);
  __hip_bfloat16* W0b = (__hip_bfloat16*)(ws + 24576000);
  __hip_bfloat16* W1b = (__hip_bfloat16*)(ws + 24637440);
  float* v3   = ws + 24735744;
  __hip_bfloat16* Wc1b = (__hip_bfloat16*)(ws + 24766464);
  __hip_bfloat16* Wc2b = (__hip_bfloat16*)(ws + 24772608);

  softmax_c_kernel<<<(M_TOK*8 + 255)/256, 256, 0, stream>>>(code, x, c_buf);
  embed_bf16_kernel<<<(M_TOK*160 + 255)/256, 256, 0, stream>>>(c_buf, codebook, A0b, 160);
  convW_kernel<<<(768*160 + 255)/256, 256, 0, stream>>>(w_ih0, W0b, 768, 150, 160);
  convW_kernel<<<(768*256 + 255)/256, 256, 0, stream>>>(w_ih1, W1b, 768, 256, 256);
  convW_kernel<<<(768*128 + 255)/256, 256, 0, stream>>>(w_hh0, Whh0b, 768, 128, 128);
  convW_kernel<<<(768*128 + 255)/256, 256, 0, stream>>>(w_hh1, Whh1b, 768, 128, 128);
  convWc_kernel<<<(128*96 + 255)/256, 256, 0, stream>>>(w1, Wc1b, 8);
  convWc_kernel<<<(128*384 + 255)/256, 256, 0, stream>>>(w2, Wc2b, 32);
  gemm_mfma_kernel<<<dim3(6,150), 256, 0, stream>>>(A0b, W0b, b_ih0, gi, 160);
  gru_scan_mfma_kernel<__hip_bfloat16><<<256, 512, 0, stream>>>(gi, Whh0b, b_hh0, h1b, 256, (size_t)128);
  gemm_mfma_kernel<<<dim3(6,150), 256, 0, stream>>>(h1b, W1b, b_ih1, gi, 256);
  gru_scan_mfma_kernel<float><<<256, 512, 0, stream>>>(gi, Whh1b, b_hh1, h2, 128, (size_t)M_TOK*HIDN);
  ln0_kernel<<<(B_SZ*8*L_SZ + 255)/256, 256, 0, stream>>>(h2, ln0g, ln0b, in_t0);
  caps_mfma_kernel<1><<<296, 256, 0, stream>>>(in_t0, Wc1b, ln1g, ln1b, (void*)v1t);
  caps_mfma_kernel<2><<<288, 256, 0, stream>>>(v1t, Wc2b, ln2g, ln2b, (void*)v2f);
  transposeW_kernel<<<(NFC*240 + 255)/256, 256, 0, stream>>>(wfc, wT);
  route_pass_kernel<0><<<dim3(NCH,B_SZ), 512, 0, stream>>>(v2f, wT, nullptr, part);
  reduce_v3_kernel<<<B_SZ, 240, 0, stream>>>(part, lnfg, lnfb, v3);
  route_pass_kernel<1><<<dim3(NCH,B_SZ), 512, 0, stream>>>(v2f, wT, v3, part);
  reduce_out_kernel<<<B_SZ, 240, 0, stream>>>(part, lnfg, lnfb, out);
}

// Round 18
// 375.498 us; speedup vs baseline: 1.0319x; 1.0319x over previous
//
#include <hip/hip_runtime.h>
#include <hip/hip_bf16.h>
#include <cstdint>

// Model constants
#define B_SZ 128
#define L_SZ 150
#define E_SZ 150
#define HIDN 128
#define M_TOK (B_SZ*L_SZ)   // 19200
#define G3 384              // 3*HID gates
#define NFC 2304            // capsule-FC input count
#define NCH 72              // n-chunks per b (32 n each)

typedef __attribute__((ext_vector_type(8))) short bf16x8;
typedef __attribute__((ext_vector_type(4))) float f32x4;

__device__ __forceinline__ float sigm(float x){ return 1.f/(1.f+__expf(-x)); }

__device__ __forceinline__ void storeval(float* p, float v){ *p = v; }
__device__ __forceinline__ void storeval(__hip_bfloat16* p, float v){ *p = __float2bfloat16(v); }

// ---------------- kernel 1: c[t][32] = softmax over last-4 of code[x[t]] ----------------
__global__ void softmax_c_kernel(const float* __restrict__ code, const int* __restrict__ x,
                                 float* __restrict__ c){
  int idx = blockIdx.x*blockDim.x + threadIdx.x;
  if (idx >= M_TOK*8) return;
  int t = idx >> 3, j = idx & 7;
  int tok = x[t];
  const float* p = code + ((size_t)tok*32 + j*4);
  float a0=p[0],a1=p[1],a2=p[2],a3=p[3];
  float mx = fmaxf(fmaxf(a0,a1),fmaxf(a2,a3));
  float e0=__expf(a0-mx),e1=__expf(a1-mx),e2=__expf(a2-mx),e3=__expf(a3-mx);
  float inv = 1.f/(e0+e1+e2+e3);
  float* q = c + ((size_t)t*32 + j*4);
  q[0]=e0*inv; q[1]=e1*inv; q[2]=e2*inv; q[3]=e3*inv;
}

// ---------------- kernel 2: emb bf16 padded ----------------
__global__ void embed_bf16_kernel(const float* __restrict__ c, const float* __restrict__ cb,
                                  __hip_bfloat16* __restrict__ A0, int Kp){
  int idx = blockIdx.x*blockDim.x + threadIdx.x;
  if (idx >= M_TOK*160) return;
  int t = idx / 160; int e = idx - t*160;
  float acc = 0.f;
  if (e < E_SZ){
    const float* cr = c + (size_t)t*32;
    #pragma unroll
    for (int i=0;i<32;i++) acc += cr[i]*cb[i*E_SZ + e];
  }
  A0[(size_t)t*Kp + e] = __float2bfloat16(acc);
}

// ---------------- fused weight prep: 7 transforms in one kernel ----------------
// seg0: w_ih0 -> W0b   (768x150 -> 768x160 pad)      122880
// seg1: w_ih1 -> W1b   (768x256 cast)                196608
// seg2: w_hh0 -> Whh0b (768x128 cast)                 98304
// seg3: w_hh1 -> Whh1b (768x128 cast)                 98304
// seg4: w1   -> Wc1b   (caps conv1, NCAPS=8)          12288
// seg5: w2   -> Wc2b   (caps conv2, NCAPS=32)         49152
// seg6: wfc  -> wT     (transpose to [n][m][d][x])   552960
// total 1,130,496
__global__ void prep_kernel(
    const float* __restrict__ w_ih0, const float* __restrict__ w_ih1,
    const float* __restrict__ w_hh0, const float* __restrict__ w_hh1,
    const float* __restrict__ w1,    const float* __restrict__ w2,
    const float* __restrict__ wfc,
    __hip_bfloat16* __restrict__ W0b,   __hip_bfloat16* __restrict__ W1b,
    __hip_bfloat16* __restrict__ Whh0b, __hip_bfloat16* __restrict__ Whh1b,
    __hip_bfloat16* __restrict__ Wc1b,  __hip_bfloat16* __restrict__ Wc2b,
    float* __restrict__ wT)
{
  int idx = blockIdx.x*blockDim.x + threadIdx.x;
  if (idx < 122880){
    int n = idx/160, k = idx - n*160;
    W0b[idx] = __float2bfloat16(k < 150 ? w_ih0[(size_t)n*150 + k] : 0.f);
    return;
  }
  idx -= 122880;
  if (idx < 196608){ W1b[idx] = __float2bfloat16(w_ih1[idx]); return; }
  idx -= 196608;
  if (idx < 98304){ Whh0b[idx] = __float2bfloat16(w_hh0[idx]); return; }
  idx -= 98304;
  if (idx < 98304){ Whh1b[idx] = __float2bfloat16(w_hh1[idx]); return; }
  idx -= 98304;
  if (idx < 12288){
    const int NCAPS = 8, KP = 96;
    int j = idx / KP; int rem = idx - j*KP;
    int k = rem/(4*NCAPS); int r2 = rem - k*4*NCAPS; int n = r2>>2; int xx = r2&3;
    int m = j>>2, d = j&3;
    Wc1b[idx] = __float2bfloat16(w1[(size_t)(((k*NCAPS+n)*4+xx)*4+d)*32 + m]);
    return;
  }
  idx -= 12288;
  if (idx < 49152){
    const int NCAPS = 32, KP = 384;
    int j = idx / KP; int rem = idx - j*KP;
    int k = rem/(4*NCAPS); int r2 = rem - k*4*NCAPS; int n = r2>>2; int xx = r2&3;
    int m = j>>2, d = j&3;
    Wc2b[idx] = __float2bfloat16(w2[(size_t)(((k*NCAPS+n)*4+xx)*4+d)*32 + m]);
    return;
  }
  idx -= 49152;
  if (idx < 552960){
    int n = idx / 240; int r = idx - n*240;
    int m = r >> 4; int dd = (r >> 2) & 3; int xx = r & 3;
    wT[idx] = wfc[(size_t)((n*4+xx)*4+dd)*15 + m];
  }
}

// ---------------- kernel 3: MFMA GEMM (input projections) ----------------
__global__ __launch_bounds__(256) void gemm_mfma_kernel(
    const __hip_bfloat16* __restrict__ A, const __hip_bfloat16* __restrict__ W,
    const float* __restrict__ bias, float* __restrict__ out, int Kp)
{
  __shared__ __hip_bfloat16 As[128*32];
  __shared__ __hip_bfloat16 Bs[128*32];
  int tid = threadIdx.x;
  int m0 = blockIdx.y*128, n0 = blockIdx.x*128;
  int lane = tid & 63, wid = tid >> 6;
  int wr = wid >> 1, wc = wid & 1;
  int srow = tid >> 2, scol = (tid & 3) * 8;

  f32x4 acc[4][4];
  #pragma unroll
  for (int i=0;i<4;i++)
    #pragma unroll
    for (int j=0;j<4;j++) acc[i][j] = (f32x4){0.f,0.f,0.f,0.f};

  int r = lane & 15, kq = (lane >> 4) * 8;

  for (int k0 = 0; k0 < Kp; k0 += 32){
    __builtin_amdgcn_global_load_lds(
      (const __attribute__((address_space(1))) void*)(A + (size_t)(m0+srow)*Kp + k0 + scol),
      (__attribute__((address_space(3))) void*)(As + tid*8), 16, 0, 0);
    __builtin_amdgcn_global_load_lds(
      (const __attribute__((address_space(1))) void*)(A + (size_t)(m0+64+srow)*Kp + k0 + scol),
      (__attribute__((address_space(3))) void*)(As + 2048 + tid*8), 16, 0, 0);
    __builtin_amdgcn_global_load_lds(
      (const __attribute__((address_space(1))) void*)(W + (size_t)(n0+srow)*Kp + k0 + scol),
      (__attribute__((address_space(3))) void*)(Bs + tid*8), 16, 0, 0);
    __builtin_amdgcn_global_load_lds(
      (const __attribute__((address_space(1))) void*)(W + (size_t)(n0+64+srow)*Kp + k0 + scol),
      (__attribute__((address_space(3))) void*)(Bs + 2048 + tid*8), 16, 0, 0);
    __syncthreads();

    bf16x8 aF[4], bF[4];
    #pragma unroll
    for (int mi=0;mi<4;mi++) aF[mi] = *(const bf16x8*)(As + (wr*64 + mi*16 + r)*32 + kq);
    #pragma unroll
    for (int nj=0;nj<4;nj++) bF[nj] = *(const bf16x8*)(Bs + (wc*64 + nj*16 + r)*32 + kq);
    #pragma unroll
    for (int mi=0;mi<4;mi++)
      #pragma unroll
      for (int nj=0;nj<4;nj++)
        acc[mi][nj] = __builtin_amdgcn_mfma_f32_16x16x32_bf16(aF[mi], bF[nj], acc[mi][nj], 0, 0, 0);
    __syncthreads();
  }

  #pragma unroll
  for (int nj=0;nj<4;nj++){
    int n = n0 + wc*64 + nj*16 + (lane & 15);
    int dir = (n >= G3) ? 1 : 0; int g = n - dir*G3;
    float bv = bias[n];
    #pragma unroll
    for (int mi=0;mi<4;mi++){
      #pragma unroll
      for (int r2=0;r2<4;r2++){
        int m = m0 + wr*64 + mi*16 + (lane>>4)*4 + r2;
        out[((size_t)dir*M_TOK + m)*G3 + g] = acc[mi][nj][r2] + bv;
      }
    }
  }
}

// ---------------- kernel 4: GRU scan v7 (R16 best) — MFMA, 8 waves ----------------
template <typename OT>
__global__ __launch_bounds__(512, 2) void gru_scan_mfma_kernel(
    const float* __restrict__ gi,            // [2][19200][384]
    const __hip_bfloat16* __restrict__ whhb, // [2][384][128] bf16
    const float* __restrict__ bhh,           // [2][384]
    OT* __restrict__ out, int rowStride, size_t dirOffset)
{
  int bx = blockIdx.x; int dir = bx>>7; int b = bx&127;
  int tid = threadIdx.x; int wid = tid>>6, lane = tid&63;
  int colr = lane & 15;
  int rowq = lane >> 4;
  __shared__ __hip_bfloat16 h_lds[2][2048];

  for (int i = tid; i < 4096; i += 512)
    ((__hip_bfloat16*)h_lds)[i] = __float2bfloat16(0.f);

  bf16x8 wF[3][4];
  #pragma unroll
  for (int g=0;g<3;g++)
    #pragma unroll
    for (int kc=0;kc<4;kc++){
      int orow = g*128 + wid*16 + colr;
      wF[g][kc] = *(const bf16x8*)(whhb + ((size_t)dir*G3 + orow)*HIDN + kc*32 + rowq*8);
    }
  #pragma unroll
  for (int g=0;g<3;g++)
    #pragma unroll
    for (int kc=0;kc<4;kc++)
      asm volatile("" : "+v"(wF[g][kc]));

  float bg_[3];
  #pragma unroll
  for (int g=0;g<3;g++)
    bg_[g] = bhh[dir*G3 + g*128 + wid*16 + colr];

  float h_old = 0.f;
  bool valid = (lane < 16);
  int j = wid*16 + colr;
  int boff = ((j>>5)*64 + ((j>>3)&3)*16)*16 + (j&7)*2;

  const float* gib = gi + ((size_t)dir*M_TOK + (size_t)b*L_SZ)*G3;

  float gv[3];
  {
    int t0 = dir ? (L_SZ-1) : 0;
    #pragma unroll
    for (int g=0;g<3;g++)
      gv[g] = valid ? gib[(size_t)t0*G3 + g*128 + j] : 0.f;
  }
  __syncthreads();

  int cur = 0;
  for (int s=0; s<L_SZ; ++s){
    int t = dir ? (L_SZ-1-s) : s;
    float gn[3] = {};
    if (s+1 < L_SZ){
      int tn = dir ? (t-1) : (t+1);
      #pragma unroll
      for (int g=0;g<3;g++)
        if (valid) gn[g] = gib[(size_t)tn*G3 + g*128 + j];
    }

    bf16x8 aF[4];
    #pragma unroll
    for (int kc=0;kc<4;kc++)
      aF[kc] = *(const bf16x8*)((const char*)h_lds[cur] + (kc*64 + lane)*16);
    f32x4 acc[3];
    #pragma unroll
    for (int g=0;g<3;g++) acc[g] = (f32x4){0.f,0.f,0.f,0.f};
    #pragma unroll
    for (int kc=0;kc<4;kc++)
      #pragma unroll
      for (int g=0;g<3;g++)
        acc[g] = __builtin_amdgcn_mfma_f32_16x16x32_bf16(aF[kc], wF[g][kc], acc[g], 0, 0, 0);

    if (valid){
      float rr = sigm(gv[0] + acc[0][0] + bg_[0]);
      float zz = sigm(gv[1] + acc[1][0] + bg_[1]);
      float xn = gv[2] + rr*(acc[2][0] + bg_[2]);
      float e2 = __expf(2.f*xn);
      float nn = 1.f - 2.f/(e2+1.f);
      float hnew = (1.f-zz)*nn + zz*h_old;
      h_old = hnew;
      *(__hip_bfloat16*)((char*)h_lds[cur^1] + boff) = __float2bfloat16(hnew);
      storeval(&out[(size_t)(b*L_SZ + t)*rowStride + (size_t)dir*dirOffset + j], hnew);
    }
    __syncthreads();
    #pragma unroll
    for (int g=0;g<3;g++) gv[g] = gn[g];
    cur ^= 1;
  }
}

// ---------------- kernel 5: ln0 -> in_t0[b][t][a][n][x] bf16 ----------------
__global__ void ln0_kernel(const float* __restrict__ h2, const float* __restrict__ g,
                           const float* __restrict__ bt, __hip_bfloat16* __restrict__ in_t0){
  int idx = blockIdx.x*blockDim.x + threadIdx.x;
  if (idx >= B_SZ*8*L_SZ) return;
  int t = idx % L_SZ; int bn = idx / L_SZ; int n = bn & 7; int b = bn >> 3;
  const float* f0 = h2 + (size_t)(b*L_SZ+t)*HIDN + n*16;
  const float* f1 = f0 + (size_t)M_TOK*HIDN;
  float v[16]; float s = 0.f;
  #pragma unroll
  for (int d=0;d<16;d++){ v[d] = f0[d] + f1[d]; s += v[d]; }
  float mu = s*(1.f/16.f);
  float q = 0.f;
  #pragma unroll
  for (int d=0;d<16;d++){ float df = v[d]-mu; q += df*df; }
  float rs = rsqrtf(q*(1.f/16.f) + 1e-5f);
  __hip_bfloat16* o = in_t0 + (size_t)b*19200 + t*128 + n*4;
  #pragma unroll
  for (int dd=0;dd<16;dd++){
    int a = dd>>2, xx = dd&3;
    o[a*32 + xx] = __float2bfloat16((v[dd]-mu)*rs*g[dd] + bt[dd]);
  }
}

// ---------------- kernel 6: capsule conv as MFMA GEMM with fused LN epilogue ----------------
template<int CONV>
__global__ __launch_bounds__(256) void caps_mfma_kernel(
    const __hip_bfloat16* __restrict__ A, const __hip_bfloat16* __restrict__ W,
    const float* __restrict__ gam, const float* __restrict__ bet,
    void* __restrict__ outv)
{
  constexpr int KP   = (CONV==1) ? 96 : 384;
  constexpr int KTAP = (CONV==1) ? 32 : 128;
  constexpr int S    = (CONV==1) ? 2 : 1;
  constexpr int H    = (CONV==1) ? 74 : 72;
  constexpr int RSTR = (CONV==1) ? 128 : 512;
  constexpr int BSTR = (CONV==1) ? 19200 : 37888;
  __shared__ __hip_bfloat16 As[128*32];
  __shared__ __hip_bfloat16 Bs[128*32];
  int tid = threadIdx.x;
  int m0 = blockIdx.x*128;
  int lane = tid&63, wid = tid>>6;
  int wr = wid>>1, wc = wid&1;
  int srow = tid>>2, scol = (tid&3)*8;

  int row1 = m0 + srow, row2 = row1 + 64;
  int bh1 = row1>>2, a1 = row1&3; int b1 = bh1/H, h1 = bh1 - b1*H;
  int bh2 = row2>>2, a2 = row2&3; int b2 = bh2/H, h2_ = bh2 - b2*H;
  const __hip_bfloat16* arow1 = A + (size_t)b1*BSTR + (size_t)(h1*S)*RSTR + a1*KTAP;
  const __hip_bfloat16* arow2 = A + (size_t)b2*BSTR + (size_t)(h2_*S)*RSTR + a2*KTAP;

  f32x4 acc[4][4];
  #pragma unroll
  for (int i=0;i<4;i++)
    #pragma unroll
    for (int j=0;j<4;j++) acc[i][j] = (f32x4){0.f,0.f,0.f,0.f};

  int r = lane&15, kq = (lane>>4)*8;

  for (int k0=0; k0<KP; k0+=32){
    int tap = k0/KTAP;
    int off = k0 - tap*KTAP + scol;
    __builtin_amdgcn_global_load_lds(
      (const __attribute__((address_space(1))) void*)(arow1 + tap*RSTR + off),
      (__attribute__((address_space(3))) void*)(As + tid*8), 16, 0, 0);
    __builtin_amdgcn_global_load_lds(
      (const __attribute__((address_space(1))) void*)(arow2 + tap*RSTR + off),
      (__attribute__((address_space(3))) void*)(As + 2048 + tid*8), 16, 0, 0);
    __builtin_amdgcn_global_load_lds(
      (const __attribute__((address_space(1))) void*)(W + (size_t)srow*KP + k0 + scol),
      (__attribute__((address_space(3))) void*)(Bs + tid*8), 16, 0, 0);
    __builtin_amdgcn_global_load_lds(
      (const __attribute__((address_space(1))) void*)(W + (size_t)(64+srow)*KP + k0 + scol),
      (__attribute__((address_space(3))) void*)(Bs + 2048 + tid*8), 16, 0, 0);
    __syncthreads();

    bf16x8 aF[4], bF[4];
    #pragma unroll
    for (int mi=0;mi<4;mi++) aF[mi] = *(const bf16x8*)(As + (wr*64 + mi*16 + r)*32 + kq);
    #pragma unroll
    for (int nj=0;nj<4;nj++) bF[nj] = *(const bf16x8*)(Bs + (wc*64 + nj*16 + r)*32 + kq);
    #pragma unroll
    for (int mi=0;mi<4;mi++)
      #pragma unroll
      for (int nj=0;nj<4;nj++)
        acc[mi][nj] = __builtin_amdgcn_mfma_f32_16x16x32_bf16(aF[mi], bF[nj], acc[mi][nj], 0, 0, 0);
    __syncthreads();
  }

  #pragma unroll
  for (int mi=0;mi<4;mi++)
    #pragma unroll
    for (int nj=0;nj<4;nj++){
      int jj = wc*64 + nj*16 + (lane&15);
      int rowb = m0 + wr*64 + mi*16 + (lane>>4)*4;
      float vv[4];
      #pragma unroll
      for (int r2=0;r2<4;r2++) vv[r2] = acc[mi][nj][r2]*(1.f/32.f);
      float s = vv[0]+vv[1]+vv[2]+vv[3];
      s += __shfl_xor(s,1); s += __shfl_xor(s,2);
      float mu = s*(1.f/16.f);
      float q = 0.f;
      #pragma unroll
      for (int r2=0;r2<4;r2++){ float df = vv[r2]-mu; q += df*df; }
      q += __shfl_xor(q,1); q += __shfl_xor(q,2);
      float rs = rsqrtf(q*(1.f/16.f) + 1e-5f);
      int d = jj&3;
      #pragma unroll
      for (int r2=0;r2<4;r2++){
        float o = (vv[r2]-mu)*rs*gam[r2*4+d] + bet[r2*4+d];
        if constexpr (CONV==1){
          ((__hip_bfloat16*)outv)[(size_t)(rowb+r2)*128 + jj] = __float2bfloat16(o);
        } else {
          int rw = rowb + r2; int bh = rw>>2, a = rw&3; int bb = bh/H, hh = bh - bb*H;
          ((float*)outv)[((size_t)bb*NFC + (jj>>2)*H + hh)*16 + a*4 + d] = o;
        }
      }
    }
}

// ---------------- kernel 8: routing pass v2 (R14 best) — (m,nl)-per-thread ----------------
#define RP_WTS 0        // 32 rows x 244 floats (7808) / accs 240x33 (7920) union
#define RP_FIS 7920     // 32 x 20
#define RP_V3S 8560     // 240
#define RP_LG  8800     // 32 x 17
#define RP_TOT 9344
template<int WITH_SM>
__global__ __launch_bounds__(512) void route_pass_kernel(
    const float* __restrict__ v2, const float* __restrict__ wT,
    const float* __restrict__ v3, float* __restrict__ part)
{
  int ch = blockIdx.x, b = blockIdx.y;
  int tid = threadIdx.x;
  int m = tid >> 5;          // 0..15 (15 inactive)
  int nl = tid & 31;
  int n0 = ch*32;
  bool act = (m < 15);

  __shared__ float smem[RP_TOT];
  float* wTs  = smem + RP_WTS;
  float* accs = smem + RP_WTS;   // union with wTs
  float* fis  = smem + RP_FIS;
  float* v3s  = smem + RP_V3S;
  float* lgs  = smem + RP_LG;

  for (int i=tid; i<32*60; i+=512){
    int row = i/60, q = i - row*60;
    ((float4*)wTs)[row*61 + q] = ((const float4*)(wT + (size_t)n0*240))[row*60 + q];
  }
  for (int i=tid; i<128; i+=512){
    int row = i>>2, q = i&3;
    ((float4*)fis)[row*5 + q] = ((const float4*)(v2 + ((size_t)b*NFC + n0)*16))[i];
  }
  if (WITH_SM && tid < 240) v3s[tid] = v3[(size_t)b*240 + tid];
  __syncthreads();

  float vt[16];
  float qk = 1.f/15.f;
  if (act){
    float4 fiv[4], wv[4];
    #pragma unroll
    for (int a=0;a<4;a++) fiv[a] = *(const float4*)&fis[nl*20 + a*4];
    #pragma unroll
    for (int d=0;d<4;d++) wv[d] = *(const float4*)&wTs[nl*244 + m*16 + d*4];
    #pragma unroll
    for (int a=0;a<4;a++)
      #pragma unroll
      for (int d=0;d<4;d++)
        vt[a*4+d] = fiv[a].x*wv[d].x + fiv[a].y*wv[d].y + fiv[a].z*wv[d].z + fiv[a].w*wv[d].w;
    if (WITH_SM){
      float lg = 0.f;
      #pragma unroll
      for (int ad=0;ad<16;ad++) lg += vt[ad]*v3s[m*16+ad];
      lgs[nl*17 + m] = lg*0.25f;
    }
  }
  if (WITH_SM){
    __syncthreads();
    if (act){
      float l[15];
      #pragma unroll
      for (int mm=0;mm<15;mm++) l[mm] = lgs[nl*17 + mm];
      float mx = l[0];
      #pragma unroll
      for (int mm=1;mm<15;mm++) mx = fmaxf(mx, l[mm]);
      float se = 0.f;
      #pragma unroll
      for (int mm=0;mm<15;mm++){ l[mm] = __expf(l[mm]-mx); se += l[mm]; }
      float inv = 1.f/se;
      float s2 = 0.f;
      #pragma unroll
      for (int mm=0;mm<15;mm++) s2 += l[mm]*inv;
      qk = (l[m]*inv)/(s2 + 1e-10f);
    }
  }
  __syncthreads();
  if (act){
    #pragma unroll
    for (int ad=0;ad<16;ad++)
      accs[(m*16+ad)*33 + nl] = qk*vt[ad];
  }
  __syncthreads();
  if (tid < 240){
    float s = 0.f;
    #pragma unroll
    for (int k=0;k<32;k++) s += accs[tid*33 + k];
    part[((size_t)b*NCH + ch)*240 + tid] = s;
  }
}

// ---------------- kernel 9: reduce partials -> LN -> v3 ----------------
__global__ __launch_bounds__(240) void reduce_v3_kernel(
    const float* __restrict__ part, const float* __restrict__ g,
    const float* __restrict__ bt, float* __restrict__ v3)
{
  int b = blockIdx.x; int tid = threadIdx.x;
  int ad = tid & 15;
  float s = 0.f;
  for (int ch=0; ch<NCH; ++ch) s += part[((size_t)b*NCH + ch)*240 + tid];
  float tot = s;
  tot += __shfl_xor(tot,1); tot += __shfl_xor(tot,2);
  tot += __shfl_xor(tot,4); tot += __shfl_xor(tot,8);
  float mu = tot*(1.f/16.f);
  float df = s - mu;
  float q = df*df;
  q += __shfl_xor(q,1); q += __shfl_xor(q,2);
  q += __shfl_xor(q,4); q += __shfl_xor(q,8);
  float rs = rsqrtf(q*(1.f/16.f) + 1e-5f);
  v3[(size_t)b*240 + tid] = df*rs*g[ad] + bt[ad];
}

// ---------------- kernel 10: reduce partials -> LN -> norm head -> out ----------------
__global__ __launch_bounds__(240) void reduce_out_kernel(
    const float* __restrict__ part, const float* __restrict__ g,
    const float* __restrict__ bt, float* __restrict__ out)
{
  int b = blockIdx.x; int tid = threadIdx.x;
  int m = tid >> 4; int ad = tid & 15;
  float s = 0.f;
  for (int ch=0; ch<NCH; ++ch) s += part[((size_t)b*NCH + ch)*240 + tid];
  float tot = s;
  tot += __shfl_xor(tot,1); tot += __shfl_xor(tot,2);
  tot += __shfl_xor(tot,4); tot += __shfl_xor(tot,8);
  float mu = tot*(1.f/16.f);
  float df = s - mu;
  float q = df*df;
  q += __shfl_xor(q,1); q += __shfl_xor(q,2);
  q += __shfl_xor(q,4); q += __shfl_xor(q,8);
  float rs = rsqrtf(q*(1.f/16.f) + 1e-5f);
  float v = df*rs*g[ad] + bt[ad];
  float q2 = v*v;
  q2 += __shfl_xor(q2,1); q2 += __shfl_xor(q2,2);
  q2 += __shfl_xor(q2,4); q2 += __shfl_xor(q2,8);
  if (ad == 0) out[(size_t)b*15 + m] = q2/(1.f+q2);
}

// =================================================================================
extern "C" void kernel_launch(void* const* d_in, const int* in_sizes, int n_in,
                              void* d_out, int out_size, void* d_ws, size_t ws_size,
                              hipStream_t stream) {
  const float* code     = (const float*)d_in[0];
  const float* codebook = (const float*)d_in[1];
  const float* w_ih0    = (const float*)d_in[2];
  const float* w_hh0    = (const float*)d_in[3];
  const float* b_ih0    = (const float*)d_in[4];
  const float* b_hh0    = (const float*)d_in[5];
  const float* w_ih1    = (const float*)d_in[6];
  const float* w_hh1    = (const float*)d_in[7];
  const float* b_ih1    = (const float*)d_in[8];
  const float* b_hh1    = (const float*)d_in[9];
  const float* ln0g     = (const float*)d_in[10];
  const float* ln0b     = (const float*)d_in[11];
  const float* w1       = (const float*)d_in[12];
  const float* ln1g     = (const float*)d_in[13];
  const float* ln1b     = (const float*)d_in[14];
  const float* w2       = (const float*)d_in[15];
  const float* ln2g     = (const float*)d_in[16];
  const float* ln2b     = (const float*)d_in[17];
  const float* wfc      = (const float*)d_in[18];
  const float* lnfg     = (const float*)d_in[19];
  const float* lnfb     = (const float*)d_in[20];
  const int*   x        = (const int*)d_in[21];
  float* out = (float*)d_out;
  float* ws  = (float*)d_ws;

  float* gi   = ws + 0;
  __hip_bfloat16* v1t = (__hip_bfloat16*)(ws + 0);
  float* v2f  = ws + 4849664;
  float* wT   = ws + 9568256;
  float* part = ws + 10121216;
  __hip_bfloat16* h1b = (__hip_bfloat16*)(ws + 14745600);
  float* h2   = ws + 17203200;
  float* c_buf= ws + 17203200;
  __hip_bfloat16* in_t0 = (__hip_bfloat16*)(ws + 22118400);
  __hip_bfloat16* A0b = (__hip_bfloat16*)(ws + 22118400);
  __hip_bfloat16* Whh0b = (__hip_bfloat16*)(ws + 23654400);
  __hip_bfloat16* Whh1b = (__hip_bfloat16*)(ws + 23703552);
  __hip_bfloat16* W0b = (__hip_bfloat16*)(ws + 24576000);
  __hip_bfloat16* W1b = (__hip_bfloat16*)(ws + 24637440);
  float* v3   = ws + 24735744;
  __hip_bfloat16* Wc1b = (__hip_bfloat16*)(ws + 24766464);
  __hip_bfloat16* Wc2b = (__hip_bfloat16*)(ws + 24772608);

  softmax_c_kernel<<<(M_TOK*8 + 255)/256, 256, 0, stream>>>(code, x, c_buf);
  embed_bf16_kernel<<<(M_TOK*160 + 255)/256, 256, 0, stream>>>(c_buf, codebook, A0b, 160);
  // fused weight prep (replaces 4x convW + 2x convWc + transposeW)
  prep_kernel<<<(1130496 + 255)/256, 256, 0, stream>>>(
      w_ih0, w_ih1, w_hh0, w_hh1, w1, w2, wfc,
      W0b, W1b, Whh0b, Whh1b, Wc1b, Wc2b, wT);
  gemm_mfma_kernel<<<dim3(6,150), 256, 0, stream>>>(A0b, W0b, b_ih0, gi, 160);
  gru_scan_mfma_kernel<__hip_bfloat16><<<256, 512, 0, stream>>>(gi, Whh0b, b_hh0, h1b, 256, (size_t)128);
  gemm_mfma_kernel<<<dim3(6,150), 256, 0, stream>>>(h1b, W1b, b_ih1, gi, 256);
  gru_scan_mfma_kernel<float><<<256, 512, 0, stream>>>(gi, Whh1b, b_hh1, h2, 128, (size_t)M_TOK*HIDN);
  ln0_kernel<<<(B_SZ*8*L_SZ + 255)/256, 256, 0, stream>>>(h2, ln0g, ln0b, in_t0);
  caps_mfma_kernel<1><<<296, 256, 0, stream>>>(in_t0, Wc1b, ln1g, ln1b, (void*)v1t);
  caps_mfma_kernel<2><<<288, 256, 0, stream>>>(v1t, Wc2b, ln2g, ln2b, (void*)v2f);
  route_pass_kernel<0><<<dim3(NCH,B_SZ), 512, 0, stream>>>(v2f, wT, nullptr, part);
  reduce_v3_kernel<<<B_SZ, 240, 0, stream>>>(part, lnfg, lnfb, v3);
  route_pass_kernel<1><<<dim3(NCH,B_SZ), 512, 0, stream>>>(v2f, wT, v3, part);
  reduce_out_kernel<<<B_SZ, 240, 0, stream>>>(part, lnfg, lnfb, out);
}

// Round 19
// 364.282 us; speedup vs baseline: 1.0636x; 1.0308x over previous
//
#include <hip/hip_runtime.h>
#include <hip/hip_bf16.h>
#include <cstdint>

// Model constants
#define B_SZ 128
#define L_SZ 150
#define E_SZ 150
#define HIDN 128
#define M_TOK (B_SZ*L_SZ)   // 19200
#define G3 384              // 3*HID gates
#define NFC 2304            // capsule-FC input count
#define NCH 72              // n-chunks per b (32 n each)

typedef __attribute__((ext_vector_type(8))) short bf16x8;
typedef __attribute__((ext_vector_type(4))) float f32x4;

__device__ __forceinline__ float sigm(float x){ return 1.f/(1.f+__expf(-x)); }

__device__ __forceinline__ void storeval(float* p, float v){ *p = v; }
__device__ __forceinline__ void storeval(__hip_bfloat16* p, float v){ *p = __float2bfloat16(v); }

// ---------------- kernel 1: c[t][32] = softmax over last-4 of code[x[t]] ----------------
__global__ void softmax_c_kernel(const float* __restrict__ code, const int* __restrict__ x,
                                 float* __restrict__ c){
  int idx = blockIdx.x*blockDim.x + threadIdx.x;
  if (idx >= M_TOK*8) return;
  int t = idx >> 3, j = idx & 7;
  int tok = x[t];
  const float* p = code + ((size_t)tok*32 + j*4);
  float a0=p[0],a1=p[1],a2=p[2],a3=p[3];
  float mx = fmaxf(fmaxf(a0,a1),fmaxf(a2,a3));
  float e0=__expf(a0-mx),e1=__expf(a1-mx),e2=__expf(a2-mx),e3=__expf(a3-mx);
  float inv = 1.f/(e0+e1+e2+e3);
  float* q = c + ((size_t)t*32 + j*4);
  q[0]=e0*inv; q[1]=e1*inv; q[2]=e2*inv; q[3]=e3*inv;
}

// ---------------- kernel 2: emb bf16 padded ----------------
__global__ void embed_bf16_kernel(const float* __restrict__ c, const float* __restrict__ cb,
                                  __hip_bfloat16* __restrict__ A0, int Kp){
  int idx = blockIdx.x*blockDim.x + threadIdx.x;
  if (idx >= M_TOK*160) return;
  int t = idx / 160; int e = idx - t*160;
  float acc = 0.f;
  if (e < E_SZ){
    const float* cr = c + (size_t)t*32;
    #pragma unroll
    for (int i=0;i<32;i++) acc += cr[i]*cb[i*E_SZ + e];
  }
  A0[(size_t)t*Kp + e] = __float2bfloat16(acc);
}

// ---------------- fused weight prep: 8 transforms in one kernel ----------------
// seg0: w_ih0 -> W0b (pad)   122880
// seg1: w_ih1 -> W1b         196608
// seg2: w_hh0 -> Whh0b        98304
// seg3: w_hh1 -> Whh1b        98304
// seg4: w1   -> Wc1b          12288
// seg5: w2   -> Wc2b          49152
// seg6: wfc  -> wT           552960
// seg7: wfc  -> Wv [64][9216] bf16 (vote-GEMM B, j=m*4+d, k=n*4+x)  589824
// total 1,720,320
__global__ void prep_kernel(
    const float* __restrict__ w_ih0, const float* __restrict__ w_ih1,
    const float* __restrict__ w_hh0, const float* __restrict__ w_hh1,
    const float* __restrict__ w1,    const float* __restrict__ w2,
    const float* __restrict__ wfc,
    __hip_bfloat16* __restrict__ W0b,   __hip_bfloat16* __restrict__ W1b,
    __hip_bfloat16* __restrict__ Whh0b, __hip_bfloat16* __restrict__ Whh1b,
    __hip_bfloat16* __restrict__ Wc1b,  __hip_bfloat16* __restrict__ Wc2b,
    float* __restrict__ wT, __hip_bfloat16* __restrict__ Wv)
{
  int idx = blockIdx.x*blockDim.x + threadIdx.x;
  if (idx < 122880){
    int n = idx/160, k = idx - n*160;
    W0b[idx] = __float2bfloat16(k < 150 ? w_ih0[(size_t)n*150 + k] : 0.f);
    return;
  }
  idx -= 122880;
  if (idx < 196608){ W1b[idx] = __float2bfloat16(w_ih1[idx]); return; }
  idx -= 196608;
  if (idx < 98304){ Whh0b[idx] = __float2bfloat16(w_hh0[idx]); return; }
  idx -= 98304;
  if (idx < 98304){ Whh1b[idx] = __float2bfloat16(w_hh1[idx]); return; }
  idx -= 98304;
  if (idx < 12288){
    const int NCAPS = 8, KP = 96;
    int j = idx / KP; int rem = idx - j*KP;
    int k = rem/(4*NCAPS); int r2 = rem - k*4*NCAPS; int n = r2>>2; int xx = r2&3;
    int m = j>>2, d = j&3;
    Wc1b[idx] = __float2bfloat16(w1[(size_t)(((k*NCAPS+n)*4+xx)*4+d)*32 + m]);
    return;
  }
  idx -= 12288;
  if (idx < 49152){
    const int NCAPS = 32, KP = 384;
    int j = idx / KP; int rem = idx - j*KP;
    int k = rem/(4*NCAPS); int r2 = rem - k*4*NCAPS; int n = r2>>2; int xx = r2&3;
    int m = j>>2, d = j&3;
    Wc2b[idx] = __float2bfloat16(w2[(size_t)(((k*NCAPS+n)*4+xx)*4+d)*32 + m]);
    return;
  }
  idx -= 49152;
  if (idx < 552960){
    int n = idx / 240; int r = idx - n*240;
    int m = r >> 4; int dd = (r >> 2) & 3; int xx = r & 3;
    wT[idx] = wfc[(size_t)((n*4+xx)*4+dd)*15 + m];
    return;
  }
  idx -= 552960;
  if (idx < 589824){
    int j = idx / 9216; int k = idx - j*9216;
    int m = j>>2, d = j&3; int n = k>>2, xx = k&3;
    Wv[idx] = __float2bfloat16(m < 15 ? wfc[(size_t)((n*4+xx)*4+d)*15 + m] : 0.f);
  }
}

// ---------------- kernel 3: MFMA GEMM (input projections) ----------------
__global__ __launch_bounds__(256) void gemm_mfma_kernel(
    const __hip_bfloat16* __restrict__ A, const __hip_bfloat16* __restrict__ W,
    const float* __restrict__ bias, float* __restrict__ out, int Kp)
{
  __shared__ __hip_bfloat16 As[128*32];
  __shared__ __hip_bfloat16 Bs[128*32];
  int tid = threadIdx.x;
  int m0 = blockIdx.y*128, n0 = blockIdx.x*128;
  int lane = tid & 63, wid = tid >> 6;
  int wr = wid >> 1, wc = wid & 1;
  int srow = tid >> 2, scol = (tid & 3) * 8;

  f32x4 acc[4][4];
  #pragma unroll
  for (int i=0;i<4;i++)
    #pragma unroll
    for (int j=0;j<4;j++) acc[i][j] = (f32x4){0.f,0.f,0.f,0.f};

  int r = lane & 15, kq = (lane >> 4) * 8;

  for (int k0 = 0; k0 < Kp; k0 += 32){
    __builtin_amdgcn_global_load_lds(
      (const __attribute__((address_space(1))) void*)(A + (size_t)(m0+srow)*Kp + k0 + scol),
      (__attribute__((address_space(3))) void*)(As + tid*8), 16, 0, 0);
    __builtin_amdgcn_global_load_lds(
      (const __attribute__((address_space(1))) void*)(A + (size_t)(m0+64+srow)*Kp + k0 + scol),
      (__attribute__((address_space(3))) void*)(As + 2048 + tid*8), 16, 0, 0);
    __builtin_amdgcn_global_load_lds(
      (const __attribute__((address_space(1))) void*)(W + (size_t)(n0+srow)*Kp + k0 + scol),
      (__attribute__((address_space(3))) void*)(Bs + tid*8), 16, 0, 0);
    __builtin_amdgcn_global_load_lds(
      (const __attribute__((address_space(1))) void*)(W + (size_t)(n0+64+srow)*Kp + k0 + scol),
      (__attribute__((address_space(3))) void*)(Bs + 2048 + tid*8), 16, 0, 0);
    __syncthreads();

    bf16x8 aF[4], bF[4];
    #pragma unroll
    for (int mi=0;mi<4;mi++) aF[mi] = *(const bf16x8*)(As + (wr*64 + mi*16 + r)*32 + kq);
    #pragma unroll
    for (int nj=0;nj<4;nj++) bF[nj] = *(const bf16x8*)(Bs + (wc*64 + nj*16 + r)*32 + kq);
    #pragma unroll
    for (int mi=0;mi<4;mi++)
      #pragma unroll
      for (int nj=0;nj<4;nj++)
        acc[mi][nj] = __builtin_amdgcn_mfma_f32_16x16x32_bf16(aF[mi], bF[nj], acc[mi][nj], 0, 0, 0);
    __syncthreads();
  }

  #pragma unroll
  for (int nj=0;nj<4;nj++){
    int n = n0 + wc*64 + nj*16 + (lane & 15);
    int dir = (n >= G3) ? 1 : 0; int g = n - dir*G3;
    float bv = bias[n];
    #pragma unroll
    for (int mi=0;mi<4;mi++){
      #pragma unroll
      for (int r2=0;r2<4;r2++){
        int m = m0 + wr*64 + mi*16 + (lane>>4)*4 + r2;
        out[((size_t)dir*M_TOK + m)*G3 + g] = acc[mi][nj][r2] + bv;
      }
    }
  }
}

// ---------------- kernel 4: GRU scan v7 (best) — MFMA, 8 waves ----------------
template <typename OT>
__global__ __launch_bounds__(512, 2) void gru_scan_mfma_kernel(
    const float* __restrict__ gi, const __hip_bfloat16* __restrict__ whhb,
    const float* __restrict__ bhh, OT* __restrict__ out, int rowStride, size_t dirOffset)
{
  int bx = blockIdx.x; int dir = bx>>7; int b = bx&127;
  int tid = threadIdx.x; int wid = tid>>6, lane = tid&63;
  int colr = lane & 15;
  int rowq = lane >> 4;
  __shared__ __hip_bfloat16 h_lds[2][2048];

  for (int i = tid; i < 4096; i += 512)
    ((__hip_bfloat16*)h_lds)[i] = __float2bfloat16(0.f);

  bf16x8 wF[3][4];
  #pragma unroll
  for (int g=0;g<3;g++)
    #pragma unroll
    for (int kc=0;kc<4;kc++){
      int orow = g*128 + wid*16 + colr;
      wF[g][kc] = *(const bf16x8*)(whhb + ((size_t)dir*G3 + orow)*HIDN + kc*32 + rowq*8);
    }
  #pragma unroll
  for (int g=0;g<3;g++)
    #pragma unroll
    for (int kc=0;kc<4;kc++)
      asm volatile("" : "+v"(wF[g][kc]));

  float bg_[3];
  #pragma unroll
  for (int g=0;g<3;g++)
    bg_[g] = bhh[dir*G3 + g*128 + wid*16 + colr];

  float h_old = 0.f;
  bool valid = (lane < 16);
  int j = wid*16 + colr;
  int boff = ((j>>5)*64 + ((j>>3)&3)*16)*16 + (j&7)*2;

  const float* gib = gi + ((size_t)dir*M_TOK + (size_t)b*L_SZ)*G3;

  float gv[3];
  {
    int t0 = dir ? (L_SZ-1) : 0;
    #pragma unroll
    for (int g=0;g<3;g++)
      gv[g] = valid ? gib[(size_t)t0*G3 + g*128 + j] : 0.f;
  }
  __syncthreads();

  int cur = 0;
  for (int s=0; s<L_SZ; ++s){
    int t = dir ? (L_SZ-1-s) : s;
    float gn[3] = {};
    if (s+1 < L_SZ){
      int tn = dir ? (t-1) : (t+1);
      #pragma unroll
      for (int g=0;g<3;g++)
        if (valid) gn[g] = gib[(size_t)tn*G3 + g*128 + j];
    }

    bf16x8 aF[4];
    #pragma unroll
    for (int kc=0;kc<4;kc++)
      aF[kc] = *(const bf16x8*)((const char*)h_lds[cur] + (kc*64 + lane)*16);
    f32x4 acc[3];
    #pragma unroll
    for (int g=0;g<3;g++) acc[g] = (f32x4){0.f,0.f,0.f,0.f};
    #pragma unroll
    for (int kc=0;kc<4;kc++)
      #pragma unroll
      for (int g=0;g<3;g++)
        acc[g] = __builtin_amdgcn_mfma_f32_16x16x32_bf16(aF[kc], wF[g][kc], acc[g], 0, 0, 0);

    if (valid){
      float rr = sigm(gv[0] + acc[0][0] + bg_[0]);
      float zz = sigm(gv[1] + acc[1][0] + bg_[1]);
      float xn = gv[2] + rr*(acc[2][0] + bg_[2]);
      float e2 = __expf(2.f*xn);
      float nn = 1.f - 2.f/(e2+1.f);
      float hnew = (1.f-zz)*nn + zz*h_old;
      h_old = hnew;
      *(__hip_bfloat16*)((char*)h_lds[cur^1] + boff) = __float2bfloat16(hnew);
      storeval(&out[(size_t)(b*L_SZ + t)*rowStride + (size_t)dir*dirOffset + j], hnew);
    }
    __syncthreads();
    #pragma unroll
    for (int g=0;g<3;g++) gv[g] = gn[g];
    cur ^= 1;
  }
}

// ---------------- kernel 5: ln0 -> in_t0[b][t][a][n][x] bf16 ----------------
__global__ void ln0_kernel(const float* __restrict__ h2, const float* __restrict__ g,
                           const float* __restrict__ bt, __hip_bfloat16* __restrict__ in_t0){
  int idx = blockIdx.x*blockDim.x + threadIdx.x;
  if (idx >= B_SZ*8*L_SZ) return;
  int t = idx % L_SZ; int bn = idx / L_SZ; int n = bn & 7; int b = bn >> 3;
  const float* f0 = h2 + (size_t)(b*L_SZ+t)*HIDN + n*16;
  const float* f1 = f0 + (size_t)M_TOK*HIDN;
  float v[16]; float s = 0.f;
  #pragma unroll
  for (int d=0;d<16;d++){ v[d] = f0[d] + f1[d]; s += v[d]; }
  float mu = s*(1.f/16.f);
  float q = 0.f;
  #pragma unroll
  for (int d=0;d<16;d++){ float df = v[d]-mu; q += df*df; }
  float rs = rsqrtf(q*(1.f/16.f) + 1e-5f);
  __hip_bfloat16* o = in_t0 + (size_t)b*19200 + t*128 + n*4;
  #pragma unroll
  for (int dd=0;dd<16;dd++){
    int a = dd>>2, xx = dd&3;
    o[a*32 + xx] = __float2bfloat16((v[dd]-mu)*rs*g[dd] + bt[dd]);
  }
}

// ---------------- kernel 6: capsule conv as MFMA GEMM with fused LN epilogue ----------------
// CONV==2 additionally writes votes-operand v2b16[(b*4+a)][n*4+d] bf16 for the vote-GEMM.
template<int CONV>
__global__ __launch_bounds__(256) void caps_mfma_kernel(
    const __hip_bfloat16* __restrict__ A, const __hip_bfloat16* __restrict__ W,
    const float* __restrict__ gam, const float* __restrict__ bet,
    void* __restrict__ outv, __hip_bfloat16* __restrict__ outb16)
{
  constexpr int KP   = (CONV==1) ? 96 : 384;
  constexpr int KTAP = (CONV==1) ? 32 : 128;
  constexpr int S    = (CONV==1) ? 2 : 1;
  constexpr int H    = (CONV==1) ? 74 : 72;
  constexpr int RSTR = (CONV==1) ? 128 : 512;
  constexpr int BSTR = (CONV==1) ? 19200 : 37888;
  __shared__ __hip_bfloat16 As[128*32];
  __shared__ __hip_bfloat16 Bs[128*32];
  int tid = threadIdx.x;
  int m0 = blockIdx.x*128;
  int lane = tid&63, wid = tid>>6;
  int wr = wid>>1, wc = wid&1;
  int srow = tid>>2, scol = (tid&3)*8;

  int row1 = m0 + srow, row2 = row1 + 64;
  int bh1 = row1>>2, a1 = row1&3; int b1 = bh1/H, h1 = bh1 - b1*H;
  int bh2 = row2>>2, a2 = row2&3; int b2 = bh2/H, h2_ = bh2 - b2*H;
  const __hip_bfloat16* arow1 = A + (size_t)b1*BSTR + (size_t)(h1*S)*RSTR + a1*KTAP;
  const __hip_bfloat16* arow2 = A + (size_t)b2*BSTR + (size_t)(h2_*S)*RSTR + a2*KTAP;

  f32x4 acc[4][4];
  #pragma unroll
  for (int i=0;i<4;i++)
    #pragma unroll
    for (int j=0;j<4;j++) acc[i][j] = (f32x4){0.f,0.f,0.f,0.f};

  int r = lane&15, kq = (lane>>4)*8;

  for (int k0=0; k0<KP; k0+=32){
    int tap = k0/KTAP;
    int off = k0 - tap*KTAP + scol;
    __builtin_amdgcn_global_load_lds(
      (const __attribute__((address_space(1))) void*)(arow1 + tap*RSTR + off),
      (__attribute__((address_space(3))) void*)(As + tid*8), 16, 0, 0);
    __builtin_amdgcn_global_load_lds(
      (const __attribute__((address_space(1))) void*)(arow2 + tap*RSTR + off),
      (__attribute__((address_space(3))) void*)(As + 2048 + tid*8), 16, 0, 0);
    __builtin_amdgcn_global_load_lds(
      (const __attribute__((address_space(1))) void*)(W + (size_t)srow*KP + k0 + scol),
      (__attribute__((address_space(3))) void*)(Bs + tid*8), 16, 0, 0);
    __builtin_amdgcn_global_load_lds(
      (const __attribute__((address_space(1))) void*)(W + (size_t)(64+srow)*KP + k0 + scol),
      (__attribute__((address_space(3))) void*)(Bs + 2048 + tid*8), 16, 0, 0);
    __syncthreads();

    bf16x8 aF[4], bF[4];
    #pragma unroll
    for (int mi=0;mi<4;mi++) aF[mi] = *(const bf16x8*)(As + (wr*64 + mi*16 + r)*32 + kq);
    #pragma unroll
    for (int nj=0;nj<4;nj++) bF[nj] = *(const bf16x8*)(Bs + (wc*64 + nj*16 + r)*32 + kq);
    #pragma unroll
    for (int mi=0;mi<4;mi++)
      #pragma unroll
      for (int nj=0;nj<4;nj++)
        acc[mi][nj] = __builtin_amdgcn_mfma_f32_16x16x32_bf16(aF[mi], bF[nj], acc[mi][nj], 0, 0, 0);
    __syncthreads();
  }

  #pragma unroll
  for (int mi=0;mi<4;mi++)
    #pragma unroll
    for (int nj=0;nj<4;nj++){
      int jj = wc*64 + nj*16 + (lane&15);
      int rowb = m0 + wr*64 + mi*16 + (lane>>4)*4;
      float vv[4];
      #pragma unroll
      for (int r2=0;r2<4;r2++) vv[r2] = acc[mi][nj][r2]*(1.f/32.f);
      float s = vv[0]+vv[1]+vv[2]+vv[3];
      s += __shfl_xor(s,1); s += __shfl_xor(s,2);
      float mu = s*(1.f/16.f);
      float q = 0.f;
      #pragma unroll
      for (int r2=0;r2<4;r2++){ float df = vv[r2]-mu; q += df*df; }
      q += __shfl_xor(q,1); q += __shfl_xor(q,2);
      float rs = rsqrtf(q*(1.f/16.f) + 1e-5f);
      int d = jj&3;
      #pragma unroll
      for (int r2=0;r2<4;r2++){
        float o = (vv[r2]-mu)*rs*gam[r2*4+d] + bet[r2*4+d];
        if constexpr (CONV==1){
          ((__hip_bfloat16*)outv)[(size_t)(rowb+r2)*128 + jj] = __float2bfloat16(o);
        } else {
          int rw = rowb + r2; int bh = rw>>2, a = rw&3; int bb = bh/H, hh = bh - bb*H;
          int n = (jj>>2)*H + hh;
          ((float*)outv)[((size_t)bb*NFC + n)*16 + a*4 + d] = o;
          outb16[((size_t)(bb*4 + a))*9216 + (size_t)n*4 + d] = __float2bfloat16(o);
        }
      }
    }
}

// ---------------- kernel 7: vote GEMM — v3pre partials via MFMA ----------------
// part[kc][row=(b*4+a)][col=(m*4+d)] = sum over K-chunk kc of A[row][K] . B[col][K]
// A = v2b16 [512][9216], B = Wv [64][9216]. grid (8 kc, 8 mt), 256 thr (4 waves).
__global__ __launch_bounds__(256) void vote_gemm_kernel(
    const __hip_bfloat16* __restrict__ A, const __hip_bfloat16* __restrict__ B,
    float* __restrict__ part)
{
  __shared__ __hip_bfloat16 As[64*32];
  __shared__ __hip_bfloat16 Bs[64*32];
  int kc = blockIdx.x, mt = blockIdx.y;
  int tid = threadIdx.x;
  int lane = tid&63, wid = tid>>6;
  int srow = tid>>2, scol = (tid&3)*8;
  int r = lane&15, kq = (lane>>4)*8;
  f32x4 acc[4];
  #pragma unroll
  for (int nj=0;nj<4;nj++) acc[nj] = (f32x4){0.f,0.f,0.f,0.f};
  size_t kbase = (size_t)kc*1152;
  for (int k0=0; k0<1152; k0+=32){
    __builtin_amdgcn_global_load_lds(
      (const __attribute__((address_space(1))) void*)(A + (size_t)(mt*64+srow)*9216 + kbase + k0 + scol),
      (__attribute__((address_space(3))) void*)(As + tid*8), 16, 0, 0);
    __builtin_amdgcn_global_load_lds(
      (const __attribute__((address_space(1))) void*)(B + (size_t)srow*9216 + kbase + k0 + scol),
      (__attribute__((address_space(3))) void*)(Bs + tid*8), 16, 0, 0);
    __syncthreads();
    bf16x8 aF = *(const bf16x8*)(As + (wid*16 + r)*32 + kq);
    bf16x8 bF[4];
    #pragma unroll
    for (int nj=0;nj<4;nj++) bF[nj] = *(const bf16x8*)(Bs + (nj*16 + r)*32 + kq);
    #pragma unroll
    for (int nj=0;nj<4;nj++)
      acc[nj] = __builtin_amdgcn_mfma_f32_16x16x32_bf16(aF, bF[nj], acc[nj], 0, 0, 0);
    __syncthreads();
  }
  #pragma unroll
  for (int nj=0;nj<4;nj++){
    int col = nj*16 + (lane&15);
    #pragma unroll
    for (int r2=0;r2<4;r2++){
      int row = mt*64 + wid*16 + (lane>>4)*4 + r2;
      part[(size_t)kc*32768 + (size_t)row*64 + col] = acc[nj][r2];
    }
  }
}

// ---------------- kernel 8: routing pass C (R14 best) — (m,nl)-per-thread ----------------
#define RP_WTS 0
#define RP_FIS 7920
#define RP_V3S 8560
#define RP_LG  8800
#define RP_TOT 9344
__global__ __launch_bounds__(512) void route_passC_kernel(
    const float* __restrict__ v2, const float* __restrict__ wT,
    const float* __restrict__ v3, float* __restrict__ part)
{
  int ch = blockIdx.x, b = blockIdx.y;
  int tid = threadIdx.x;
  int m = tid >> 5;
  int nl = tid & 31;
  int n0 = ch*32;
  bool act = (m < 15);

  __shared__ float smem[RP_TOT];
  float* wTs  = smem + RP_WTS;
  float* accs = smem + RP_WTS;   // union with wTs
  float* fis  = smem + RP_FIS;
  float* v3s  = smem + RP_V3S;
  float* lgs  = smem + RP_LG;

  for (int i=tid; i<32*60; i+=512){
    int row = i/60, q = i - row*60;
    ((float4*)wTs)[row*61 + q] = ((const float4*)(wT + (size_t)n0*240))[row*60 + q];
  }
  for (int i=tid; i<128; i+=512){
    int row = i>>2, q = i&3;
    ((float4*)fis)[row*5 + q] = ((const float4*)(v2 + ((size_t)b*NFC + n0)*16))[i];
  }
  if (tid < 240) v3s[tid] = v3[(size_t)b*240 + tid];
  __syncthreads();

  float vt[16];
  float qk = 1.f/15.f;
  if (act){
    float4 fiv[4], wv[4];
    #pragma unroll
    for (int a=0;a<4;a++) fiv[a] = *(const float4*)&fis[nl*20 + a*4];
    #pragma unroll
    for (int d=0;d<4;d++) wv[d] = *(const float4*)&wTs[nl*244 + m*16 + d*4];
    #pragma unroll
    for (int a=0;a<4;a++)
      #pragma unroll
      for (int d=0;d<4;d++)
        vt[a*4+d] = fiv[a].x*wv[d].x + fiv[a].y*wv[d].y + fiv[a].z*wv[d].z + fiv[a].w*wv[d].w;
    float lg = 0.f;
    #pragma unroll
    for (int ad=0;ad<16;ad++) lg += vt[ad]*v3s[m*16+ad];
    lgs[nl*17 + m] = lg*0.25f;
  }
  __syncthreads();
  if (act){
    float l[15];
    #pragma unroll
    for (int mm=0;mm<15;mm++) l[mm] = lgs[nl*17 + mm];
    float mx = l[0];
    #pragma unroll
    for (int mm=1;mm<15;mm++) mx = fmaxf(mx, l[mm]);
    float se = 0.f;
    #pragma unroll
    for (int mm=0;mm<15;mm++){ l[mm] = __expf(l[mm]-mx); se += l[mm]; }
    float inv = 1.f/se;
    float s2 = 0.f;
    #pragma unroll
    for (int mm=0;mm<15;mm++) s2 += l[mm]*inv;
    qk = (l[m]*inv)/(s2 + 1e-10f);
  }
  __syncthreads();
  if (act){
    #pragma unroll
    for (int ad=0;ad<16;ad++)
      accs[(m*16+ad)*33 + nl] = qk*vt[ad];
  }
  __syncthreads();
  if (tid < 240){
    float s = 0.f;
    #pragma unroll
    for (int k=0;k<32;k++) s += accs[tid*33 + k];
    part[((size_t)b*NCH + ch)*240 + tid] = s;
  }
}

// ---------------- kernel 9: reduce vote partials -> LN -> v3 ----------------
__global__ __launch_bounds__(240) void reduce_v3_kernel(
    const float* __restrict__ part, const float* __restrict__ g,
    const float* __restrict__ bt, float* __restrict__ v3)
{
  int b = blockIdx.x; int tid = threadIdx.x;
  int m = tid >> 4; int ad = tid & 15; int a = ad >> 2; int d = ad & 3;
  int row = b*4 + a; int col = m*4 + d;
  float s = 0.f;
  #pragma unroll
  for (int kc=0;kc<8;kc++) s += part[(size_t)kc*32768 + (size_t)row*64 + col];
  s *= (1.f/15.f);
  float tot = s;
  tot += __shfl_xor(tot,1); tot += __shfl_xor(tot,2);
  tot += __shfl_xor(tot,4); tot += __shfl_xor(tot,8);
  float mu = tot*(1.f/16.f);
  float df = s - mu;
  float q = df*df;
  q += __shfl_xor(q,1); q += __shfl_xor(q,2);
  q += __shfl_xor(q,4); q += __shfl_xor(q,8);
  float rs = rsqrtf(q*(1.f/16.f) + 1e-5f);
  v3[(size_t)b*240 + tid] = df*rs*g[ad] + bt[ad];
}

// ---------------- kernel 10: reduce partials -> LN -> norm head -> out ----------------
__global__ __launch_bounds__(240) void reduce_out_kernel(
    const float* __restrict__ part, const float* __restrict__ g,
    const float* __restrict__ bt, float* __restrict__ out)
{
  int b = blockIdx.x; int tid = threadIdx.x;
  int m = tid >> 4; int ad = tid & 15;
  float s = 0.f;
  for (int ch=0; ch<NCH; ++ch) s += part[((size_t)b*NCH + ch)*240 + tid];
  float tot = s;
  tot += __shfl_xor(tot,1); tot += __shfl_xor(tot,2);
  tot += __shfl_xor(tot,4); tot += __shfl_xor(tot,8);
  float mu = tot*(1.f/16.f);
  float df = s - mu;
  float q = df*df;
  q += __shfl_xor(q,1); q += __shfl_xor(q,2);
  q += __shfl_xor(q,4); q += __shfl_xor(q,8);
  float rs = rsqrtf(q*(1.f/16.f) + 1e-5f);
  float v = df*rs*g[ad] + bt[ad];
  float q2 = v*v;
  q2 += __shfl_xor(q2,1); q2 += __shfl_xor(q2,2);
  q2 += __shfl_xor(q2,4); q2 += __shfl_xor(q2,8);
  if (ad == 0) out[(size_t)b*15 + m] = q2/(1.f+q2);
}

// =================================================================================
extern "C" void kernel_launch(void* const* d_in, const int* in_sizes, int n_in,
                              void* d_out, int out_size, void* d_ws, size_t ws_size,
                              hipStream_t stream) {
  const float* code     = (const float*)d_in[0];
  const float* codebook = (const float*)d_in[1];
  const float* w_ih0    = (const float*)d_in[2];
  const float* w_hh0    = (const float*)d_in[3];
  const float* b_ih0    = (const float*)d_in[4];
  const float* b_hh0    = (const float*)d_in[5];
  const float* w_ih1    = (const float*)d_in[6];
  const float* w_hh1    = (const float*)d_in[7];
  const float* b_ih1    = (const float*)d_in[8];
  const float* b_hh1    = (const float*)d_in[9];
  const float* ln0g     = (const float*)d_in[10];
  const float* ln0b     = (const float*)d_in[11];
  const float* w1       = (const float*)d_in[12];
  const float* ln1g     = (const float*)d_in[13];
  const float* ln1b     = (const float*)d_in[14];
  const float* w2       = (const float*)d_in[15];
  const float* ln2g     = (const float*)d_in[16];
  const float* ln2b     = (const float*)d_in[17];
  const float* wfc      = (const float*)d_in[18];
  const float* lnfg     = (const float*)d_in[19];
  const float* lnfb     = (const float*)d_in[20];
  const int*   x        = (const int*)d_in[21];
  float* out = (float*)d_out;
  float* ws  = (float*)d_ws;

  float* gi   = ws + 0;
  __hip_bfloat16* v1t = (__hip_bfloat16*)(ws + 0);
  float* v2f  = ws + 4849664;
  float* wT   = ws + 9568256;
  float* part = ws + 10121216;                         // vote partials 262,144 f / route 2,211,840 f
  __hip_bfloat16* h1b = (__hip_bfloat16*)(ws + 14745600);
  float* h2   = ws + 17203200;
  float* c_buf= ws + 17203200;
  __hip_bfloat16* in_t0 = (__hip_bfloat16*)(ws + 22118400);
  __hip_bfloat16* A0b = (__hip_bfloat16*)(ws + 22118400);
  __hip_bfloat16* Whh0b = (__hip_bfloat16*)(ws + 23654400);
  __hip_bfloat16* Whh1b = (__hip_bfloat16*)(ws + 23703552);
  __hip_bfloat16* W0b = (__hip_bfloat16*)(ws + 24576000);
  __hip_bfloat16* W1b = (__hip_bfloat16*)(ws + 24637440);
  float* v3   = ws + 24735744;
  __hip_bfloat16* Wc1b = (__hip_bfloat16*)(ws + 24766464);
  __hip_bfloat16* Wc2b = (__hip_bfloat16*)(ws + 24772608);   // ends 24,797,184
  __hip_bfloat16* v2b16 = (__hip_bfloat16*)(ws + 24797184);  // 4,718,592 bf16 -> ends 27,156,480
  __hip_bfloat16* Wv    = (__hip_bfloat16*)(ws + 27156480);  //   589,824 bf16 -> ends 27,451,392

  softmax_c_kernel<<<(M_TOK*8 + 255)/256, 256, 0, stream>>>(code, x, c_buf);
  embed_bf16_kernel<<<(M_TOK*160 + 255)/256, 256, 0, stream>>>(c_buf, codebook, A0b, 160);
  prep_kernel<<<(1720320 + 255)/256, 256, 0, stream>>>(
      w_ih0, w_ih1, w_hh0, w_hh1, w1, w2, wfc,
      W0b, W1b, Whh0b, Whh1b, Wc1b, Wc2b, wT, Wv);
  gemm_mfma_kernel<<<dim3(6,150), 256, 0, stream>>>(A0b, W0b, b_ih0, gi, 160);
  gru_scan_mfma_kernel<__hip_bfloat16><<<256, 512, 0, stream>>>(gi, Whh0b, b_hh0, h1b, 256, (size_t)128);
  gemm_mfma_kernel<<<dim3(6,150), 256, 0, stream>>>(h1b, W1b, b_ih1, gi, 256);
  gru_scan_mfma_kernel<float><<<256, 512, 0, stream>>>(gi, Whh1b, b_hh1, h2, 128, (size_t)M_TOK*HIDN);
  ln0_kernel<<<(B_SZ*8*L_SZ + 255)/256, 256, 0, stream>>>(h2, ln0g, ln0b, in_t0);
  caps_mfma_kernel<1><<<296, 256, 0, stream>>>(in_t0, Wc1b, ln1g, ln1b, (void*)v1t, nullptr);
  caps_mfma_kernel<2><<<288, 256, 0, stream>>>(v1t, Wc2b, ln2g, ln2b, (void*)v2f, v2b16);
  // pass A as MFMA vote-GEMM (replaces route_pass<0>)
  vote_gemm_kernel<<<dim3(8,8), 256, 0, stream>>>(v2b16, Wv, part);
  reduce_v3_kernel<<<B_SZ, 240, 0, stream>>>(part, lnfg, lnfb, v3);
  route_passC_kernel<<<dim3(NCH,B_SZ), 512, 0, stream>>>(v2f, wT, v3, part);
  reduce_out_kernel<<<B_SZ, 240, 0, stream>>>(part, lnfg, lnfb, out);
}

// Round 20
// 355.268 us; speedup vs baseline: 1.0906x; 1.0254x over previous
//
#include <hip/hip_runtime.h>
#include <hip/hip_bf16.h>
#include <cstdint>

// Model constants
#define B_SZ 128
#define L_SZ 150
#define E_SZ 150
#define HIDN 128
#define M_TOK (B_SZ*L_SZ)   // 19200
#define G3 384              // 3*HID gates
#define NFC 2304            // capsule-FC input count
#define NCH 72              // n-chunks per b (32 n each)

typedef __attribute__((ext_vector_type(8))) short bf16x8;
typedef __attribute__((ext_vector_type(4))) float f32x4;

__device__ __forceinline__ float sigm(float x){ return 1.f/(1.f+__expf(-x)); }

__device__ __forceinline__ void storeval(float* p, float v){ *p = v; }
__device__ __forceinline__ void storeval(__hip_bfloat16* p, float v){ *p = __float2bfloat16(v); }

// ---------------- kernel 1: c[t][32] = softmax over last-4 of code[x[t]] ----------------
__global__ void softmax_c_kernel(const float* __restrict__ code, const int* __restrict__ x,
                                 float* __restrict__ c){
  int idx = blockIdx.x*blockDim.x + threadIdx.x;
  if (idx >= M_TOK*8) return;
  int t = idx >> 3, j = idx & 7;
  int tok = x[t];
  const float* p = code + ((size_t)tok*32 + j*4);
  float a0=p[0],a1=p[1],a2=p[2],a3=p[3];
  float mx = fmaxf(fmaxf(a0,a1),fmaxf(a2,a3));
  float e0=__expf(a0-mx),e1=__expf(a1-mx),e2=__expf(a2-mx),e3=__expf(a3-mx);
  float inv = 1.f/(e0+e1+e2+e3);
  float* q = c + ((size_t)t*32 + j*4);
  q[0]=e0*inv; q[1]=e1*inv; q[2]=e2*inv; q[3]=e3*inv;
}

// ---------------- kernel 2: emb bf16 padded ----------------
__global__ void embed_bf16_kernel(const float* __restrict__ c, const float* __restrict__ cb,
                                  __hip_bfloat16* __restrict__ A0, int Kp){
  int idx = blockIdx.x*blockDim.x + threadIdx.x;
  if (idx >= M_TOK*160) return;
  int t = idx / 160; int e = idx - t*160;
  float acc = 0.f;
  if (e < E_SZ){
    const float* cr = c + (size_t)t*32;
    #pragma unroll
    for (int i=0;i<32;i++) acc += cr[i]*cb[i*E_SZ + e];
  }
  A0[(size_t)t*Kp + e] = __float2bfloat16(acc);
}

// ---------------- fused weight prep: 8 transforms in one kernel ----------------
__global__ void prep_kernel(
    const float* __restrict__ w_ih0, const float* __restrict__ w_ih1,
    const float* __restrict__ w_hh0, const float* __restrict__ w_hh1,
    const float* __restrict__ w1,    const float* __restrict__ w2,
    const float* __restrict__ wfc,
    __hip_bfloat16* __restrict__ W0b,   __hip_bfloat16* __restrict__ W1b,
    __hip_bfloat16* __restrict__ Whh0b, __hip_bfloat16* __restrict__ Whh1b,
    __hip_bfloat16* __restrict__ Wc1b,  __hip_bfloat16* __restrict__ Wc2b,
    float* __restrict__ wT, __hip_bfloat16* __restrict__ Wv)
{
  int idx = blockIdx.x*blockDim.x + threadIdx.x;
  if (idx < 122880){
    int n = idx/160, k = idx - n*160;
    W0b[idx] = __float2bfloat16(k < 150 ? w_ih0[(size_t)n*150 + k] : 0.f);
    return;
  }
  idx -= 122880;
  if (idx < 196608){ W1b[idx] = __float2bfloat16(w_ih1[idx]); return; }
  idx -= 196608;
  if (idx < 98304){ Whh0b[idx] = __float2bfloat16(w_hh0[idx]); return; }
  idx -= 98304;
  if (idx < 98304){ Whh1b[idx] = __float2bfloat16(w_hh1[idx]); return; }
  idx -= 98304;
  if (idx < 12288){
    const int NCAPS = 8, KP = 96;
    int j = idx / KP; int rem = idx - j*KP;
    int k = rem/(4*NCAPS); int r2 = rem - k*4*NCAPS; int n = r2>>2; int xx = r2&3;
    int m = j>>2, d = j&3;
    Wc1b[idx] = __float2bfloat16(w1[(size_t)(((k*NCAPS+n)*4+xx)*4+d)*32 + m]);
    return;
  }
  idx -= 12288;
  if (idx < 49152){
    const int NCAPS = 32, KP = 384;
    int j = idx / KP; int rem = idx - j*KP;
    int k = rem/(4*NCAPS); int r2 = rem - k*4*NCAPS; int n = r2>>2; int xx = r2&3;
    int m = j>>2, d = j&3;
    Wc2b[idx] = __float2bfloat16(w2[(size_t)(((k*NCAPS+n)*4+xx)*4+d)*32 + m]);
    return;
  }
  idx -= 49152;
  if (idx < 552960){
    int n = idx / 240; int r = idx - n*240;
    int m = r >> 4; int dd = (r >> 2) & 3; int xx = r & 3;
    wT[idx] = wfc[(size_t)((n*4+xx)*4+dd)*15 + m];
    return;
  }
  idx -= 552960;
  if (idx < 589824){
    int j = idx / 9216; int k = idx - j*9216;
    int m = j>>2, d = j&3; int n = k>>2, xx = k&3;
    Wv[idx] = __float2bfloat16(m < 15 ? wfc[(size_t)((n*4+xx)*4+d)*15 + m] : 0.f);
  }
}

// ---------------- kernel 3: MFMA GEMM (input projections) ----------------
__global__ __launch_bounds__(256) void gemm_mfma_kernel(
    const __hip_bfloat16* __restrict__ A, const __hip_bfloat16* __restrict__ W,
    const float* __restrict__ bias, float* __restrict__ out, int Kp)
{
  __shared__ __hip_bfloat16 As[128*32];
  __shared__ __hip_bfloat16 Bs[128*32];
  int tid = threadIdx.x;
  int m0 = blockIdx.y*128, n0 = blockIdx.x*128;
  int lane = tid & 63, wid = tid >> 6;
  int wr = wid >> 1, wc = wid & 1;
  int srow = tid >> 2, scol = (tid & 3) * 8;

  f32x4 acc[4][4];
  #pragma unroll
  for (int i=0;i<4;i++)
    #pragma unroll
    for (int j=0;j<4;j++) acc[i][j] = (f32x4){0.f,0.f,0.f,0.f};

  int r = lane & 15, kq = (lane >> 4) * 8;

  for (int k0 = 0; k0 < Kp; k0 += 32){
    __builtin_amdgcn_global_load_lds(
      (const __attribute__((address_space(1))) void*)(A + (size_t)(m0+srow)*Kp + k0 + scol),
      (__attribute__((address_space(3))) void*)(As + tid*8), 16, 0, 0);
    __builtin_amdgcn_global_load_lds(
      (const __attribute__((address_space(1))) void*)(A + (size_t)(m0+64+srow)*Kp + k0 + scol),
      (__attribute__((address_space(3))) void*)(As + 2048 + tid*8), 16, 0, 0);
    __builtin_amdgcn_global_load_lds(
      (const __attribute__((address_space(1))) void*)(W + (size_t)(n0+srow)*Kp + k0 + scol),
      (__attribute__((address_space(3))) void*)(Bs + tid*8), 16, 0, 0);
    __builtin_amdgcn_global_load_lds(
      (const __attribute__((address_space(1))) void*)(W + (size_t)(n0+64+srow)*Kp + k0 + scol),
      (__attribute__((address_space(3))) void*)(Bs + 2048 + tid*8), 16, 0, 0);
    __syncthreads();

    bf16x8 aF[4], bF[4];
    #pragma unroll
    for (int mi=0;mi<4;mi++) aF[mi] = *(const bf16x8*)(As + (wr*64 + mi*16 + r)*32 + kq);
    #pragma unroll
    for (int nj=0;nj<4;nj++) bF[nj] = *(const bf16x8*)(Bs + (wc*64 + nj*16 + r)*32 + kq);
    #pragma unroll
    for (int mi=0;mi<4;mi++)
      #pragma unroll
      for (int nj=0;nj<4;nj++)
        acc[mi][nj] = __builtin_amdgcn_mfma_f32_16x16x32_bf16(aF[mi], bF[nj], acc[mi][nj], 0, 0, 0);
    __syncthreads();
  }

  #pragma unroll
  for (int nj=0;nj<4;nj++){
    int n = n0 + wc*64 + nj*16 + (lane & 15);
    int dir = (n >= G3) ? 1 : 0; int g = n - dir*G3;
    float bv = bias[n];
    #pragma unroll
    for (int mi=0;mi<4;mi++){
      #pragma unroll
      for (int r2=0;r2<4;r2++){
        int m = m0 + wr*64 + mi*16 + (lane>>4)*4 + r2;
        out[((size_t)dir*M_TOK + m)*G3 + g] = acc[mi][nj][r2] + bv;
      }
    }
  }
}

// ---------------- kernel 4: GRU scan v7 (best) — MFMA, 8 waves ----------------
template <typename OT>
__global__ __launch_bounds__(512, 2) void gru_scan_mfma_kernel(
    const float* __restrict__ gi, const __hip_bfloat16* __restrict__ whhb,
    const float* __restrict__ bhh, OT* __restrict__ out, int rowStride, size_t dirOffset)
{
  int bx = blockIdx.x; int dir = bx>>7; int b = bx&127;
  int tid = threadIdx.x; int wid = tid>>6, lane = tid&63;
  int colr = lane & 15;
  int rowq = lane >> 4;
  __shared__ __hip_bfloat16 h_lds[2][2048];

  for (int i = tid; i < 4096; i += 512)
    ((__hip_bfloat16*)h_lds)[i] = __float2bfloat16(0.f);

  bf16x8 wF[3][4];
  #pragma unroll
  for (int g=0;g<3;g++)
    #pragma unroll
    for (int kc=0;kc<4;kc++){
      int orow = g*128 + wid*16 + colr;
      wF[g][kc] = *(const bf16x8*)(whhb + ((size_t)dir*G3 + orow)*HIDN + kc*32 + rowq*8);
    }
  #pragma unroll
  for (int g=0;g<3;g++)
    #pragma unroll
    for (int kc=0;kc<4;kc++)
      asm volatile("" : "+v"(wF[g][kc]));

  float bg_[3];
  #pragma unroll
  for (int g=0;g<3;g++)
    bg_[g] = bhh[dir*G3 + g*128 + wid*16 + colr];

  float h_old = 0.f;
  bool valid = (lane < 16);
  int j = wid*16 + colr;
  int boff = ((j>>5)*64 + ((j>>3)&3)*16)*16 + (j&7)*2;

  const float* gib = gi + ((size_t)dir*M_TOK + (size_t)b*L_SZ)*G3;

  float gv[3];
  {
    int t0 = dir ? (L_SZ-1) : 0;
    #pragma unroll
    for (int g=0;g<3;g++)
      gv[g] = valid ? gib[(size_t)t0*G3 + g*128 + j] : 0.f;
  }
  __syncthreads();

  int cur = 0;
  for (int s=0; s<L_SZ; ++s){
    int t = dir ? (L_SZ-1-s) : s;
    float gn[3] = {};
    if (s+1 < L_SZ){
      int tn = dir ? (t-1) : (t+1);
      #pragma unroll
      for (int g=0;g<3;g++)
        if (valid) gn[g] = gib[(size_t)tn*G3 + g*128 + j];
    }

    bf16x8 aF[4];
    #pragma unroll
    for (int kc=0;kc<4;kc++)
      aF[kc] = *(const bf16x8*)((const char*)h_lds[cur] + (kc*64 + lane)*16);
    f32x4 acc[3];
    #pragma unroll
    for (int g=0;g<3;g++) acc[g] = (f32x4){0.f,0.f,0.f,0.f};
    #pragma unroll
    for (int kc=0;kc<4;kc++)
      #pragma unroll
      for (int g=0;g<3;g++)
        acc[g] = __builtin_amdgcn_mfma_f32_16x16x32_bf16(aF[kc], wF[g][kc], acc[g], 0, 0, 0);

    if (valid){
      float rr = sigm(gv[0] + acc[0][0] + bg_[0]);
      float zz = sigm(gv[1] + acc[1][0] + bg_[1]);
      float xn = gv[2] + rr*(acc[2][0] + bg_[2]);
      float e2 = __expf(2.f*xn);
      float nn = 1.f - 2.f/(e2+1.f);
      float hnew = (1.f-zz)*nn + zz*h_old;
      h_old = hnew;
      *(__hip_bfloat16*)((char*)h_lds[cur^1] + boff) = __float2bfloat16(hnew);
      storeval(&out[(size_t)(b*L_SZ + t)*rowStride + (size_t)dir*dirOffset + j], hnew);
    }
    __syncthreads();
    #pragma unroll
    for (int g=0;g<3;g++) gv[g] = gn[g];
    cur ^= 1;
  }
}

// ---------------- kernel 5: ln0 -> in_t0[b][t][a][n][x] bf16 ----------------
__global__ void ln0_kernel(const float* __restrict__ h2, const float* __restrict__ g,
                           const float* __restrict__ bt, __hip_bfloat16* __restrict__ in_t0){
  int idx = blockIdx.x*blockDim.x + threadIdx.x;
  if (idx >= B_SZ*8*L_SZ) return;
  int t = idx % L_SZ; int bn = idx / L_SZ; int n = bn & 7; int b = bn >> 3;
  const float* f0 = h2 + (size_t)(b*L_SZ+t)*HIDN + n*16;
  const float* f1 = f0 + (size_t)M_TOK*HIDN;
  float v[16]; float s = 0.f;
  #pragma unroll
  for (int d=0;d<16;d++){ v[d] = f0[d] + f1[d]; s += v[d]; }
  float mu = s*(1.f/16.f);
  float q = 0.f;
  #pragma unroll
  for (int d=0;d<16;d++){ float df = v[d]-mu; q += df*df; }
  float rs = rsqrtf(q*(1.f/16.f) + 1e-5f);
  __hip_bfloat16* o = in_t0 + (size_t)b*19200 + t*128 + n*4;
  #pragma unroll
  for (int dd=0;dd<16;dd++){
    int a = dd>>2, xx = dd&3;
    o[a*32 + xx] = __float2bfloat16((v[dd]-mu)*rs*g[dd] + bt[dd]);
  }
}

// ---------------- kernel 6: capsule conv as MFMA GEMM with fused LN epilogue ----------------
template<int CONV>
__global__ __launch_bounds__(256) void caps_mfma_kernel(
    const __hip_bfloat16* __restrict__ A, const __hip_bfloat16* __restrict__ W,
    const float* __restrict__ gam, const float* __restrict__ bet,
    void* __restrict__ outv, __hip_bfloat16* __restrict__ outb16)
{
  constexpr int KP   = (CONV==1) ? 96 : 384;
  constexpr int KTAP = (CONV==1) ? 32 : 128;
  constexpr int S    = (CONV==1) ? 2 : 1;
  constexpr int H    = (CONV==1) ? 74 : 72;
  constexpr int RSTR = (CONV==1) ? 128 : 512;
  constexpr int BSTR = (CONV==1) ? 19200 : 37888;
  __shared__ __hip_bfloat16 As[128*32];
  __shared__ __hip_bfloat16 Bs[128*32];
  int tid = threadIdx.x;
  int m0 = blockIdx.x*128;
  int lane = tid&63, wid = tid>>6;
  int wr = wid>>1, wc = wid&1;
  int srow = tid>>2, scol = (tid&3)*8;

  int row1 = m0 + srow, row2 = row1 + 64;
  int bh1 = row1>>2, a1 = row1&3; int b1 = bh1/H, h1 = bh1 - b1*H;
  int bh2 = row2>>2, a2 = row2&3; int b2 = bh2/H, h2_ = bh2 - b2*H;
  const __hip_bfloat16* arow1 = A + (size_t)b1*BSTR + (size_t)(h1*S)*RSTR + a1*KTAP;
  const __hip_bfloat16* arow2 = A + (size_t)b2*BSTR + (size_t)(h2_*S)*RSTR + a2*KTAP;

  f32x4 acc[4][4];
  #pragma unroll
  for (int i=0;i<4;i++)
    #pragma unroll
    for (int j=0;j<4;j++) acc[i][j] = (f32x4){0.f,0.f,0.f,0.f};

  int r = lane&15, kq = (lane>>4)*8;

  for (int k0=0; k0<KP; k0+=32){
    int tap = k0/KTAP;
    int off = k0 - tap*KTAP + scol;
    __builtin_amdgcn_global_load_lds(
      (const __attribute__((address_space(1))) void*)(arow1 + tap*RSTR + off),
      (__attribute__((address_space(3))) void*)(As + tid*8), 16, 0, 0);
    __builtin_amdgcn_global_load_lds(
      (const __attribute__((address_space(1))) void*)(arow2 + tap*RSTR + off),
      (__attribute__((address_space(3))) void*)(As + 2048 + tid*8), 16, 0, 0);
    __builtin_amdgcn_global_load_lds(
      (const __attribute__((address_space(1))) void*)(W + (size_t)srow*KP + k0 + scol),
      (__attribute__((address_space(3))) void*)(Bs + tid*8), 16, 0, 0);
    __builtin_amdgcn_global_load_lds(
      (const __attribute__((address_space(1))) void*)(W + (size_t)(64+srow)*KP + k0 + scol),
      (__attribute__((address_space(3))) void*)(Bs + 2048 + tid*8), 16, 0, 0);
    __syncthreads();

    bf16x8 aF[4], bF[4];
    #pragma unroll
    for (int mi=0;mi<4;mi++) aF[mi] = *(const bf16x8*)(As + (wr*64 + mi*16 + r)*32 + kq);
    #pragma unroll
    for (int nj=0;nj<4;nj++) bF[nj] = *(const bf16x8*)(Bs + (wc*64 + nj*16 + r)*32 + kq);
    #pragma unroll
    for (int mi=0;mi<4;mi++)
      #pragma unroll
      for (int nj=0;nj<4;nj++)
        acc[mi][nj] = __builtin_amdgcn_mfma_f32_16x16x32_bf16(aF[mi], bF[nj], acc[mi][nj], 0, 0, 0);
    __syncthreads();
  }

  #pragma unroll
  for (int mi=0;mi<4;mi++)
    #pragma unroll
    for (int nj=0;nj<4;nj++){
      int jj = wc*64 + nj*16 + (lane&15);
      int rowb = m0 + wr*64 + mi*16 + (lane>>4)*4;
      float vv[4];
      #pragma unroll
      for (int r2=0;r2<4;r2++) vv[r2] = acc[mi][nj][r2]*(1.f/32.f);
      float s = vv[0]+vv[1]+vv[2]+vv[3];
      s += __shfl_xor(s,1); s += __shfl_xor(s,2);
      float mu = s*(1.f/16.f);
      float q = 0.f;
      #pragma unroll
      for (int r2=0;r2<4;r2++){ float df = vv[r2]-mu; q += df*df; }
      q += __shfl_xor(q,1); q += __shfl_xor(q,2);
      float rs = rsqrtf(q*(1.f/16.f) + 1e-5f);
      int d = jj&3;
      #pragma unroll
      for (int r2=0;r2<4;r2++){
        float o = (vv[r2]-mu)*rs*gam[r2*4+d] + bet[r2*4+d];
        if constexpr (CONV==1){
          ((__hip_bfloat16*)outv)[(size_t)(rowb+r2)*128 + jj] = __float2bfloat16(o);
        } else {
          int rw = rowb + r2; int bh = rw>>2, a = rw&3; int bb = bh/H, hh = bh - bb*H;
          int n = (jj>>2)*H + hh;
          ((float*)outv)[((size_t)bb*NFC + n)*16 + a*4 + d] = o;
          outb16[((size_t)(bb*4 + a))*9216 + (size_t)n*4 + d] = __float2bfloat16(o);
        }
      }
    }
}

// ---------------- kernel 7: vote GEMM — v3pre partials via MFMA ----------------
__global__ __launch_bounds__(256) void vote_gemm_kernel(
    const __hip_bfloat16* __restrict__ A, const __hip_bfloat16* __restrict__ B,
    float* __restrict__ part)
{
  __shared__ __hip_bfloat16 As[64*32];
  __shared__ __hip_bfloat16 Bs[64*32];
  int kc = blockIdx.x, mt = blockIdx.y;
  int tid = threadIdx.x;
  int lane = tid&63, wid = tid>>6;
  int srow = tid>>2, scol = (tid&3)*8;
  int r = lane&15, kq = (lane>>4)*8;
  f32x4 acc[4];
  #pragma unroll
  for (int nj=0;nj<4;nj++) acc[nj] = (f32x4){0.f,0.f,0.f,0.f};
  size_t kbase = (size_t)kc*1152;
  for (int k0=0; k0<1152; k0+=32){
    __builtin_amdgcn_global_load_lds(
      (const __attribute__((address_space(1))) void*)(A + (size_t)(mt*64+srow)*9216 + kbase + k0 + scol),
      (__attribute__((address_space(3))) void*)(As + tid*8), 16, 0, 0);
    __builtin_amdgcn_global_load_lds(
      (const __attribute__((address_space(1))) void*)(B + (size_t)srow*9216 + kbase + k0 + scol),
      (__attribute__((address_space(3))) void*)(Bs + tid*8), 16, 0, 0);
    __syncthreads();
    bf16x8 aF = *(const bf16x8*)(As + (wid*16 + r)*32 + kq);
    bf16x8 bF[4];
    #pragma unroll
    for (int nj=0;nj<4;nj++) bF[nj] = *(const bf16x8*)(Bs + (nj*16 + r)*32 + kq);
    #pragma unroll
    for (int nj=0;nj<4;nj++)
      acc[nj] = __builtin_amdgcn_mfma_f32_16x16x32_bf16(aF, bF[nj], acc[nj], 0, 0, 0);
    __syncthreads();
  }
  #pragma unroll
  for (int nj=0;nj<4;nj++){
    int col = nj*16 + (lane&15);
    #pragma unroll
    for (int r2=0;r2<4;r2++){
      int row = mt*64 + wid*16 + (lane>>4)*4 + r2;
      part[(size_t)kc*32768 + (size_t)row*64 + col] = acc[nj][r2];
    }
  }
}

// ---------------- kernel 8: routing pass C v3 — direct-global wv (no wTs staging) ----------------
// R20: wTs had ZERO cross-thread reuse (each float read by exactly one thread once),
// so the LDS round-trip (stage loop + barrier + read) was pure overhead. Thread (m,nl)
// now loads its wv[4] straight from L2-hot wT. fis (12x reuse) and v3s stay in LDS.
// One fewer barrier (no wTs/accs union hazard).
#define RC_ACC 0        // 240 x 33 = 7920
#define RC_FIS 7920     // 32 x 20  = 640
#define RC_V3S 8560     // 240
#define RC_LG  8800     // 32 x 17  = 544
#define RC_TOT 9344
__global__ __launch_bounds__(512) void route_passC_kernel(
    const float* __restrict__ v2, const float* __restrict__ wT,
    const float* __restrict__ v3, float* __restrict__ part)
{
  int ch = blockIdx.x, b = blockIdx.y;
  int tid = threadIdx.x;
  int m = tid >> 5;
  int nl = tid & 31;
  int n0 = ch*32;
  bool act = (m < 15);

  __shared__ float smem[RC_TOT];
  float* accs = smem + RC_ACC;
  float* fis  = smem + RC_FIS;
  float* v3s  = smem + RC_V3S;
  float* lgs  = smem + RC_LG;

  // issue per-thread weight loads early (L2-hot; drains under fis staging + barrier)
  float4 wv[4];
  if (act){
    const float4* wvp = (const float4*)(wT + (size_t)(n0 + nl)*240 + m*16);
    #pragma unroll
    for (int d=0;d<4;d++) wv[d] = wvp[d];
  }
  for (int i=tid; i<128; i+=512){
    int row = i>>2, q = i&3;
    ((float4*)fis)[row*5 + q] = ((const float4*)(v2 + ((size_t)b*NFC + n0)*16))[i];
  }
  if (tid < 240) v3s[tid] = v3[(size_t)b*240 + tid];
  __syncthreads();

  float vt[16];
  float qk = 1.f/15.f;
  if (act){
    float4 fiv[4];
    #pragma unroll
    for (int a=0;a<4;a++) fiv[a] = *(const float4*)&fis[nl*20 + a*4];
    #pragma unroll
    for (int a=0;a<4;a++)
      #pragma unroll
      for (int d=0;d<4;d++)
        vt[a*4+d] = fiv[a].x*wv[d].x + fiv[a].y*wv[d].y + fiv[a].z*wv[d].z + fiv[a].w*wv[d].w;
    float lg = 0.f;
    #pragma unroll
    for (int ad=0;ad<16;ad++) lg += vt[ad]*v3s[m*16+ad];
    lgs[nl*17 + m] = lg*0.25f;
  }
  __syncthreads();
  if (act){
    float l[15];
    #pragma unroll
    for (int mm=0;mm<15;mm++) l[mm] = lgs[nl*17 + mm];
    float mx = l[0];
    #pragma unroll
    for (int mm=1;mm<15;mm++) mx = fmaxf(mx, l[mm]);
    float se = 0.f;
    #pragma unroll
    for (int mm=0;mm<15;mm++){ l[mm] = __expf(l[mm]-mx); se += l[mm]; }
    float inv = 1.f/se;
    float s2 = 0.f;
    #pragma unroll
    for (int mm=0;mm<15;mm++) s2 += l[mm]*inv;
    qk = (l[m]*inv)/(s2 + 1e-10f);
    #pragma unroll
    for (int ad=0;ad<16;ad++)
      accs[(m*16+ad)*33 + nl] = qk*vt[ad];
  }
  __syncthreads();
  if (tid < 240){
    float s = 0.f;
    #pragma unroll
    for (int k=0;k<32;k++) s += accs[tid*33 + k];
    part[((size_t)b*NCH + ch)*240 + tid] = s;
  }
}

// ---------------- kernel 9: reduce vote partials -> LN -> v3 ----------------
__global__ __launch_bounds__(240) void reduce_v3_kernel(
    const float* __restrict__ part, const float* __restrict__ g,
    const float* __restrict__ bt, float* __restrict__ v3)
{
  int b = blockIdx.x; int tid = threadIdx.x;
  int m = tid >> 4; int ad = tid & 15; int a = ad >> 2; int d = ad & 3;
  int row = b*4 + a; int col = m*4 + d;
  float s = 0.f;
  #pragma unroll
  for (int kc=0;kc<8;kc++) s += part[(size_t)kc*32768 + (size_t)row*64 + col];
  s *= (1.f/15.f);
  float tot = s;
  tot += __shfl_xor(tot,1); tot += __shfl_xor(tot,2);
  tot += __shfl_xor(tot,4); tot += __shfl_xor(tot,8);
  float mu = tot*(1.f/16.f);
  float df = s - mu;
  float q = df*df;
  q += __shfl_xor(q,1); q += __shfl_xor(q,2);
  q += __shfl_xor(q,4); q += __shfl_xor(q,8);
  float rs = rsqrtf(q*(1.f/16.f) + 1e-5f);
  v3[(size_t)b*240 + tid] = df*rs*g[ad] + bt[ad];
}

// ---------------- kernel 10: reduce partials -> LN -> norm head -> out ----------------
__global__ __launch_bounds__(240) void reduce_out_kernel(
    const float* __restrict__ part, const float* __restrict__ g,
    const float* __restrict__ bt, float* __restrict__ out)
{
  int b = blockIdx.x; int tid = threadIdx.x;
  int m = tid >> 4; int ad = tid & 15;
  float s = 0.f;
  for (int ch=0; ch<NCH; ++ch) s += part[((size_t)b*NCH + ch)*240 + tid];
  float tot = s;
  tot += __shfl_xor(tot,1); tot += __shfl_xor(tot,2);
  tot += __shfl_xor(tot,4); tot += __shfl_xor(tot,8);
  float mu = tot*(1.f/16.f);
  float df = s - mu;
  float q = df*df;
  q += __shfl_xor(q,1); q += __shfl_xor(q,2);
  q += __shfl_xor(q,4); q += __shfl_xor(q,8);
  float rs = rsqrtf(q*(1.f/16.f) + 1e-5f);
  float v = df*rs*g[ad] + bt[ad];
  float q2 = v*v;
  q2 += __shfl_xor(q2,1); q2 += __shfl_xor(q2,2);
  q2 += __shfl_xor(q2,4); q2 += __shfl_xor(q2,8);
  if (ad == 0) out[(size_t)b*15 + m] = q2/(1.f+q2);
}

// =================================================================================
extern "C" void kernel_launch(void* const* d_in, const int* in_sizes, int n_in,
                              void* d_out, int out_size, void* d_ws, size_t ws_size,
                              hipStream_t stream) {
  const float* code     = (const float*)d_in[0];
  const float* codebook = (const float*)d_in[1];
  const float* w_ih0    = (const float*)d_in[2];
  const float* w_hh0    = (const float*)d_in[3];
  const float* b_ih0    = (const float*)d_in[4];
  const float* b_hh0    = (const float*)d_in[5];
  const float* w_ih1    = (const float*)d_in[6];
  const float* w_hh1    = (const float*)d_in[7];
  const float* b_ih1    = (const float*)d_in[8];
  const float* b_hh1    = (const float*)d_in[9];
  const float* ln0g     = (const float*)d_in[10];
  const float* ln0b     = (const float*)d_in[11];
  const float* w1       = (const float*)d_in[12];
  const float* ln1g     = (const float*)d_in[13];
  const float* ln1b     = (const float*)d_in[14];
  const float* w2       = (const float*)d_in[15];
  const float* ln2g     = (const float*)d_in[16];
  const float* ln2b     = (const float*)d_in[17];
  const float* wfc      = (const float*)d_in[18];
  const float* lnfg     = (const float*)d_in[19];
  const float* lnfb     = (const float*)d_in[20];
  const int*   x        = (const int*)d_in[21];
  float* out = (float*)d_out;
  float* ws  = (float*)d_ws;

  float* gi   = ws + 0;
  __hip_bfloat16* v1t = (__hip_bfloat16*)(ws + 0);
  float* v2f  = ws + 4849664;
  float* wT   = ws + 9568256;
  float* part = ws + 10121216;
  __hip_bfloat16* h1b = (__hip_bfloat16*)(ws + 14745600);
  float* h2   = ws + 17203200;
  float* c_buf= ws + 17203200;
  __hip_bfloat16* in_t0 = (__hip_bfloat16*)(ws + 22118400);
  __hip_bfloat16* A0b = (__hip_bfloat16*)(ws + 22118400);
  __hip_bfloat16* Whh0b = (__hip_bfloat16*)(ws + 23654400);
  __hip_bfloat16* Whh1b = (__hip_bfloat16*)(ws + 23703552);
  __hip_bfloat16* W0b = (__hip_bfloat16*)(ws + 24576000);
  __hip_bfloat16* W1b = (__hip_bfloat16*)(ws + 24637440);
  float* v3   = ws + 24735744;
  __hip_bfloat16* Wc1b = (__hip_bfloat16*)(ws + 24766464);
  __hip_bfloat16* Wc2b = (__hip_bfloat16*)(ws + 24772608);
  __hip_bfloat16* v2b16 = (__hip_bfloat16*)(ws + 24797184);
  __hip_bfloat16* Wv    = (__hip_bfloat16*)(ws + 27156480);

  softmax_c_kernel<<<(M_TOK*8 + 255)/256, 256, 0, stream>>>(code, x, c_buf);
  embed_bf16_kernel<<<(M_TOK*160 + 255)/256, 256, 0, stream>>>(c_buf, codebook, A0b, 160);
  prep_kernel<<<(1720320 + 255)/256, 256, 0, stream>>>(
      w_ih0, w_ih1, w_hh0, w_hh1, w1, w2, wfc,
      W0b, W1b, Whh0b, Whh1b, Wc1b, Wc2b, wT, Wv);
  gemm_mfma_kernel<<<dim3(6,150), 256, 0, stream>>>(A0b, W0b, b_ih0, gi, 160);
  gru_scan_mfma_kernel<__hip_bfloat16><<<256, 512, 0, stream>>>(gi, Whh0b, b_hh0, h1b, 256, (size_t)128);
  gemm_mfma_kernel<<<dim3(6,150), 256, 0, stream>>>(h1b, W1b, b_ih1, gi, 256);
  gru_scan_mfma_kernel<float><<<256, 512, 0, stream>>>(gi, Whh1b, b_hh1, h2, 128, (size_t)M_TOK*HIDN);
  ln0_kernel<<<(B_SZ*8*L_SZ + 255)/256, 256, 0, stream>>>(h2, ln0g, ln0b, in_t0);
  caps_mfma_kernel<1><<<296, 256, 0, stream>>>(in_t0, Wc1b, ln1g, ln1b, (void*)v1t, nullptr);
  caps_mfma_kernel<2><<<288, 256, 0, stream>>>(v1t, Wc2b, ln2g, ln2b, (void*)v2f, v2b16);
  vote_gemm_kernel<<<dim3(8,8), 256, 0, stream>>>(v2b16, Wv, part);
  reduce_v3_kernel<<<B_SZ, 240, 0, stream>>>(part, lnfg, lnfb, v3);
  route_passC_kernel<<<dim3(NCH,B_SZ), 512, 0, stream>>>(v2f, wT, v3, part);
  reduce_out_kernel<<<B_SZ, 240, 0, stream>>>(part, lnfg, lnfb, out);
}